// Round 12
// baseline (2899.099 us; speedup 1.0000x reference)
//
#include <hip/hip_runtime.h>
#include <cfloat>

// ---------------------------------------------------------------------------
// SearchTransfer (TTSR): 3-level patch correlation + argmax + gather/fold.
// Levels: 0 = lv3 (C=256,H=64,k=3,s=1,p=1,D=2304)
//         1 = lv2 (C=128,H=128,k=6,s=2,p=2,D=4608)
//         2 = lv1 (C=64,H=256,k=12,s=4,p=4,D=9216)
//
// score(l,m) = ninv[m]*G[l,m] - mval*P[l] - mval*ninv[m]*csum[m] + D*mval^2
// lev0: bf16x3 split, 6 products (exact argmax chain), k_g0 256x128
//       counted-vmcnt schedule, both batches one dispatch.
// lev1/2: single bf16 (NSP=1), 1 product, 256^2 BK=64 counted-vmcnt k_g8_64.
// Splits fused with row-stats (k_splitf).
// ---------------------------------------------------------------------------

typedef short short8 __attribute__((ext_vector_type(8)));
typedef float f32x4  __attribute__((ext_vector_type(4)));

template<int LEV> struct LT;
template<> struct LT<0> { static constexpr int C=256, H=64,  K=3,  S=1, P=1; };
template<> struct LT<1> { static constexpr int C=128, H=128, K=6,  S=2, P=2; };
template<> struct LT<2> { static constexpr int C=64,  H=256, K=12, S=4, P=4; };

__host__ __device__ constexpr int lev_D(int lev){ return lev==0?2304:(lev==1?4608:9216); }
// ws float-index offsets
// [0,192): scalar slots: lev*64 + q*16 + slot (q:0=sum_rs,1=ssq_rs,2=sum_lr,3=ssq_lr)
// 200+lev: mval  204+lev: scale  208: gy2_lev0  212+lev: gx2
__host__ __device__ constexpr int rho_off(int lev){ return 256 + (lev>0?2*2304:0) + (lev>1?2*4608:0); }
__host__ __device__ constexpr int p_off(int lev)   { return 32512  + lev*8192;   }
__host__ __device__ constexpr int ninv_off(int lev){ return 57088  + lev*8192;   }
__host__ __device__ constexpr int csum_off(int lev){ return 81664  + lev*8192;   }
__host__ __device__ constexpr int pmax_off(int lev){ return 106240 + lev*262144; }
__host__ __device__ constexpr int parg_off(int lev){ return 892672 + lev*262144; }
__host__ __device__ constexpr int arg_off(){ return 1679104; }
static constexpr size_t G_BASE_BYTES      = 8ull  << 20;
static constexpr size_t CHUNK_PLANE_BYTES = 72ull << 20;

__device__ inline unsigned short f2bf(float f){
    unsigned int u = __float_as_uint(f);
    return (unsigned short)((u + 0x7fffu + ((u >> 16) & 1u)) >> 16);
}
__device__ inline float bf2f(unsigned short h){ return __uint_as_float(((unsigned)h) << 16); }

#define GLOAD16(g, l) __builtin_amdgcn_global_load_lds( \
    (const __attribute__((address_space(1))) unsigned int*)(g), \
    (__attribute__((address_space(3))) unsigned int*)(l), 16, 0, 0)

__device__ __forceinline__ void barx(){
    __builtin_amdgcn_sched_barrier(0);
    __builtin_amdgcn_s_barrier();
    __builtin_amdgcn_sched_barrier(0);
}

// --- per-(b,d) row norm of refsr unfold + rs scalar slots ---
template<int LEV>
__global__ void k_rownorm(const float* __restrict__ refsr, float* __restrict__ ws){
    constexpr int C=LT<LEV>::C, H=LT<LEV>::H, K=LT<LEV>::K, S=LT<LEV>::S, PD=LT<LEV>::P;
    constexpr int D = C*K*K, KK=K*K;
    __shared__ float sh0[4], sh1[4];
    int tid = threadIdx.x, lane = tid & 63, w = tid >> 6;
    int wid = (blockIdx.x*blockDim.x + tid) >> 6;
    int b = wid / D, d = wid % D;
    int c = d/KK, rem = d%KK, ki = rem/K, kj = rem%K;
    const float* img = refsr + (size_t)(b*C + c)*H*H;
    float sum=0.f, ssq=0.f;
    for (int idx=lane; idx<4096; idx+=64){
        int ho=idx>>6, wo=idx&63;
        int row = ho*S+ki-PD, col = wo*S+kj-PD;
        if (row>=0 && row<H && col>=0 && col<H){
            float v = img[row*H+col]; sum += v; ssq += v*v;
        }
    }
    #pragma unroll
    for (int off=32; off; off>>=1){ sum += __shfl_xor(sum,off); ssq += __shfl_xor(ssq,off); }
    if (lane==0){
        float rinv = 1.0f / fmaxf(sqrtf(ssq), 1e-12f);
        ws[rho_off(LEV) + b*D + d] = rinv;
        sh0[w] = sum*rinv;
        sh1[w] = ssq*rinv*rinv;
    }
    __syncthreads();
    if (tid==0){
        int s = blockIdx.x & 15;
        atomicAdd(&ws[LEV*64 + 0*16 + s], sh0[0]+sh0[1]+sh0[2]+sh0[3]);
        atomicAdd(&ws[LEV*64 + 1*16 + s], sh1[0]+sh1[1]+sh1[2]+sh1[3]);
    }
}

template<int LEV>
__global__ void k_scalar_early(float* __restrict__ ws){
    if (threadIdx.x || blockIdx.x) return;
    float s0=0.f, s1=0.f;
    for (int s=0;s<16;s++){ s0 += ws[LEV*64+s]; s1 += ws[LEV*64+16+s]; }
    float BDL = 2.0f * (float)lev_D(LEV) * 4096.0f;
    float m = s0 / BDL;
    ws[200+LEV] = m;
    ws[212+LEV] = s1 - 2.f*m*s0 + BDL*m*m;
}

// --- FUSED bf16 split (NSP planes) + row stats. One block per row l. ---
template<int LEV, bool ISA, int NSP>
__global__ void k_splitf(const float* __restrict__ img4, const float* __restrict__ ws,
                         unsigned short* __restrict__ base,
                         float* __restrict__ dst, float* __restrict__ dst2,
                         int b, int kb0, int kd, int first){
    constexpr int C=LT<LEV>::C, H=LT<LEV>::H, K=LT<LEV>::K, S=LT<LEV>::S, PD=LT<LEV>::P;
    constexpr int KK=K*K;
    const size_t PS = (size_t)4096 * kd;
    __shared__ float s0[4], s1[4];
    const int tid = threadIdx.x, lane = tid & 63, w = tid >> 6;
    const int l = blockIdx.x;
    const int ly = l>>6, lx = l&63;
    const float* img = img4 + (size_t)b*C*H*H;
    const float* rinv = ws + rho_off(LEV) + b*lev_D(LEV);
    const int kslots = kd >> 3;
    float sum = 0.f, ssq = 0.f;
    const int iters = (kslots + 255) >> 8;
    for (int it = 0; it < iters; ++it){
        int si = it*256 + tid;
        if (si < kslots){
            int kl0 = si*8;
            unsigned short h[NSP][8];
            #pragma unroll
            for (int j=0;j<8;j++){
                int k = kb0 + kl0 + j; int c=k/KK, rem=k%KK, ki=rem/K, kj=rem%K;
                int row=ly*S+ki-PD, col=lx*S+kj-PD;
                float x = (row>=0 && row<H && col>=0 && col<H)
                          ? img[(size_t)(c*H+row)*H+col] : 0.f;
                if (ISA) x *= rinv[k];
                unsigned short a = f2bf(x); h[0][j]=a;
                float rec = bf2f(a);
                if (NSP>=2){
                    float r = x - bf2f(a);
                    unsigned short m = f2bf(r); h[1][j]=m;
                    rec += bf2f(m);
                    if (NSP==3){
                        float r2 = r - bf2f(m);
                        unsigned short c2 = f2bf(r2); h[2][j]=c2;
                        rec += bf2f(c2);
                    }
                }
                sum += rec; ssq += rec*rec;
            }
            int slot = (kl0>>3)&3, sw = slot ^ ((l>>1)&3);
            size_t off = (size_t)l*kd + (size_t)(kl0 & ~31) + sw*8;
            #pragma unroll
            for (int q=0;q<NSP;q++){
                uint4 u;
                u.x=h[q][0]|((unsigned)h[q][1]<<16); u.y=h[q][2]|((unsigned)h[q][3]<<16);
                u.z=h[q][4]|((unsigned)h[q][5]<<16); u.w=h[q][6]|((unsigned)h[q][7]<<16);
                *(uint4*)(base + q*PS + off) = u;
            }
        }
    }
    #pragma unroll
    for (int off=32; off; off>>=1){ sum += __shfl_xor(sum,off); ssq += __shfl_xor(ssq,off); }
    if (lane==0){ s0[w]=sum; s1[w]=ssq; }
    __syncthreads();
    if (tid==0){
        float ts = s0[0]+s0[1]+s0[2]+s0[3];
        float tq = s1[0]+s1[1]+s1[2]+s1[3];
        int o = b*4096 + l;
        if (ISA){
            if (first) dst[o] = ts; else dst[o] += ts;
        } else {
            if (first){ dst[o] = ts; dst2[o] = tq; }
            else      { dst[o] += ts; dst2[o] += tq; }
        }
    }
}

// --- per-(lev, b=b0+blockIdx.y): ssq -> ninv in place; lr scalar slots ---
template<int LEV>
__global__ void k_levfin(float* __restrict__ ws, int b0){
    __shared__ float r0[4], r1[4];
    int tid = threadIdx.x, lane = tid & 63, w = tid >> 6;
    int b = b0 + blockIdx.y;
    int m = blockIdx.x*256 + tid;
    float ssq = ws[ninv_off(LEV) + b*4096 + m];
    float ninv = 1.0f / fmaxf(sqrtf(ssq), 1e-12f);
    ws[ninv_off(LEV) + b*4096 + m] = ninv;
    float y0 = ws[csum_off(LEV) + b*4096 + m] * ninv;
    float y1 = ssq * ninv * ninv;
    #pragma unroll
    for (int off=32; off; off>>=1){ y0 += __shfl_xor(y0,off); y1 += __shfl_xor(y1,off); }
    if (lane==0){ r0[w]=y0; r1[w]=y1; }
    __syncthreads();
    if (tid==0){
        int s = blockIdx.x & 15;
        atomicAdd(&ws[LEV*64 + 2*16 + s], r0[0]+r0[1]+r0[2]+r0[3]);
        atomicAdd(&ws[LEV*64 + 3*16 + s], r1[0]+r1[1]+r1[2]+r1[3]);
    }
}

// --- all three levels' scales (preserves ym3 bug: lev1 uses lev0's gy2) ---
__global__ void k_scalar_late_all(float* __restrict__ ws){
    if (threadIdx.x || blockIdx.x) return;
    float gy2_0 = 0.f;
    for (int lev=0; lev<3; lev++){
        float s2=0.f, s3=0.f;
        for (int s=0;s<16;s++){ s2 += ws[lev*64+32+s]; s3 += ws[lev*64+48+s]; }
        float BDL = 2.0f * (float)lev_D(lev) * 4096.0f;
        float m = ws[200+lev];
        float gy2 = s3 - 2.f*m*s2 + BDL*m*m;
        if (lev==0) gy2_0 = gy2;
        float gx2 = ws[212+lev];
        float gyu = (lev==1) ? gy2_0 : gy2;
        ws[204+lev] = 1.0f/(sqrtf(gx2)*sqrtf(gyu));
    }
}

// ===========================================================================
// lev0 256(l)x128(m) counted-vmcnt GEMM, NSP=3 both sides (6 products),
// fused score/max/argmax. 512 thr, 144KB LDS, both batches via blockIdx.z.
// ===========================================================================
__launch_bounds__(512, 1)
__global__ void k_g0(const unsigned short* __restrict__ planes0,
                     float* __restrict__ ws, int kd){
    const size_t PS = (size_t)4096 * kd;
    const int b = blockIdx.z;
    const unsigned short* planes = planes0 + (size_t)b*6*PS;
    __shared__ unsigned short lds[2*36864];   // 144 KB
    const int tid = threadIdx.x;
    const int w = tid >> 6, lane = tid & 63;
    const int mblk = blockIdx.x, lblk = blockIdx.y;
    const int wm = w >> 2, wn = w & 3;
    const int colrow = lane & 15, rgrp = lane >> 4;
    const int swz = (rgrp ^ ((lane >> 1) & 3)) * 8;
    const int abase = wm*4096 + colrow*32 + swz;          // + p*8192 + i*512
    const int bbase = 24576 + wn*1024 + colrow*32 + swz;  // + p*4096 + j*512
    const int NT = kd >> 5;

    f32x4 acc[8][2];
    #pragma unroll
    for (int i=0;i<8;i++){ acc[i][0]=(f32x4){0,0,0,0}; acc[i][1]=(f32x4){0,0,0,0}; }

    short8 bF[3][2];

#define STAGE0(bufv, k0v, qv) do { \
    int f = w*9 + (qv); \
    int isA = f < 48; \
    int p  = isA ? (f>>4) : ((f-48)>>3); \
    int rb = isA ? ((f&15)<<4) : (((f-48)&7)<<4); \
    const unsigned short* g = planes + (size_t)(isA ? p : 3+p)*PS \
        + (size_t)((isA ? (lblk<<8) : (mblk<<7)) + rb + (lane>>2))*kd \
        + (size_t)(k0v) + (lane&3)*8; \
    unsigned short* lp = (unsigned short*)&lds[(bufv)*36864 \
        + (isA ? p*8192 : 24576 + p*4096) + rb*32]; \
    GLOAD16(g, lp); \
} while(0)

#define RDB0(bufv) do { \
    _Pragma("unroll") \
    for (int p=0;p<3;p++) \
        _Pragma("unroll") \
        for (int j=0;j<2;j++) \
            bF[p][j] = *(const short8*)&lds[(bufv)*36864 + bbase + p*4096 + j*512]; \
} while(0)

#define MMI(bufv, i) do { \
    short8 a0 = *(const short8*)&lds[(bufv)*36864 + 0*8192 + abase + (i)*512]; \
    short8 a1 = *(const short8*)&lds[(bufv)*36864 + 1*8192 + abase + (i)*512]; \
    short8 a2 = *(const short8*)&lds[(bufv)*36864 + 2*8192 + abase + (i)*512]; \
    __builtin_amdgcn_s_setprio(1); \
    _Pragma("unroll") \
    for (int j=0;j<2;j++){ \
        acc[i][j] = __builtin_amdgcn_mfma_f32_16x16x32_bf16(a0, bF[0][j], acc[i][j],0,0,0); \
        acc[i][j] = __builtin_amdgcn_mfma_f32_16x16x32_bf16(a0, bF[1][j], acc[i][j],0,0,0); \
        acc[i][j] = __builtin_amdgcn_mfma_f32_16x16x32_bf16(a1, bF[0][j], acc[i][j],0,0,0); \
        acc[i][j] = __builtin_amdgcn_mfma_f32_16x16x32_bf16(a0, bF[2][j], acc[i][j],0,0,0); \
        acc[i][j] = __builtin_amdgcn_mfma_f32_16x16x32_bf16(a1, bF[1][j], acc[i][j],0,0,0); \
        acc[i][j] = __builtin_amdgcn_mfma_f32_16x16x32_bf16(a2, bF[0][j], acc[i][j],0,0,0); \
    } \
    __builtin_amdgcn_s_setprio(0); \
} while(0)

    STAGE0(0,0,0); STAGE0(0,0,1); STAGE0(0,0,2); STAGE0(0,0,3); STAGE0(0,0,4);
    STAGE0(0,0,5); STAGE0(0,0,6); STAGE0(0,0,7); STAGE0(0,0,8);

    int cur = 0;
    for (int kt = 0; kt < NT-1; kt++){
        const int k0n = (kt+1) << 5;
        STAGE0(cur^1, k0n, 0); STAGE0(cur^1, k0n, 1); STAGE0(cur^1, k0n, 2);
        asm volatile("s_waitcnt vmcnt(3)" ::: "memory");
        barx();
        RDB0(cur);
        MMI(cur,0); MMI(cur,1);
        STAGE0(cur^1, k0n, 3); STAGE0(cur^1, k0n, 4); STAGE0(cur^1, k0n, 5);
        MMI(cur,2); MMI(cur,3); MMI(cur,4);
        STAGE0(cur^1, k0n, 6); STAGE0(cur^1, k0n, 7); STAGE0(cur^1, k0n, 8);
        MMI(cur,5); MMI(cur,6); MMI(cur,7);
        barx();
        cur ^= 1;
    }
    asm volatile("s_waitcnt vmcnt(0)" ::: "memory");
    barx();
    RDB0(cur);
    MMI(cur,0); MMI(cur,1); MMI(cur,2); MMI(cur,3);
    MMI(cur,4); MMI(cur,5); MMI(cur,6); MMI(cur,7);

#undef STAGE0
#undef RDB0
#undef MMI

    const int lbase = (lblk<<8) + wm*128;
    const int mbase = (mblk<<7) + wn*32;
    const int D = kd;
    const float mval = ws[200];
    const float Dm2 = (float)D * mval * mval;
    const float* Pv  = ws + p_off(0)    + b*4096;
    const float* NIv = ws + ninv_off(0) + b*4096;
    const float* CSv = ws + csum_off(0) + b*4096;
    barx();
    float* smax = (float*)lds;                 // [2][128]
    int*   sarg = (int*)((char*)lds + 1024);   // [2][128]
    #pragma unroll
    for (int j=0;j<2;j++){
        int m = mbase + j*16 + colrow;
        float nv = NIv[m];
        float cmv = -mval*nv*CSv[m] + Dm2;
        float v = -FLT_MAX; int vi = 0x7fffffff;
        #pragma unroll
        for (int i=0;i<8;i++){
            #pragma unroll
            for (int rg=0; rg<4; rg++){
                int l = lbase + i*16 + rgrp*4 + rg;
                float sc = nv*acc[i][j][rg] - mval*Pv[l] + cmv;
                if (sc > v){ v = sc; vi = l; }
            }
        }
        #pragma unroll
        for (int off=16; off<64; off<<=1){
            float ov = __shfl_xor(v, off);
            int   oi = __shfl_xor(vi, off);
            if (ov > v || (ov == v && oi < vi)){ v = ov; vi = oi; }
        }
        if (rgrp == 0){
            smax[wm*128 + wn*32 + j*16 + colrow] = v;
            sarg[wm*128 + wn*32 + j*16 + colrow] = vi;
        }
    }
    barx();
    if (tid < 128){
        float v0 = smax[tid];     int a0 = sarg[tid];
        float v1 = smax[128+tid]; int a1 = sarg[128+tid];
        if (v1 > v0 || (v1 == v0 && a1 < a0)){ v0 = v1; a0 = a1; }
        int o = (b*32 + lblk)*4096 + (mblk<<7) + tid;
        ws[pmax_off(0) + o] = v0;
        ((int*)ws)[parg_off(0) + o] = a0;
    }
}

// ===========================================================================
// NEW: NSP=1 256^2 BK=64 counted-vmcnt GEMM, fused score/max/argmax (MODE0).
// 512 thr, 128KB LDS (1 block/CU), 64 MFMA + 24 ds_read per wave per barrier
// pair. b = b0 + blockIdx.z, per-batch plane stride bstride (shorts).
// LDS layout per buf (shorts): side*16384 + (rowblk*2+kc)*512 subtiles of
// [16 rows][32 k] with slot swizzle inherited from global planes.
// ===========================================================================
template<int LEV>
__launch_bounds__(512, 1)
__global__ void k_g8_64(const unsigned short* __restrict__ planes0,
                        float* __restrict__ ws, int b0, int kd, size_t bstride){
    const size_t PS = (size_t)4096 * kd;
    const int b = b0 + blockIdx.z;
    const unsigned short* planes = planes0 + (size_t)blockIdx.z * bstride;
    __shared__ unsigned short lds[2*32768];   // 128 KB
    const int tid = threadIdx.x;
    const int w = tid >> 6, lane = tid & 63;
    const int mblk = blockIdx.x, lblk = blockIdx.y;
    const int wm = w >> 2, wn = w & 3;
    const int colrow = lane & 15, rgrp = lane >> 4;
    const int swz = (rgrp ^ ((lane >> 1) & 3)) * 8;
    const int abase = wm*8192 + colrow*32 + swz;            // + i*1024 + h*512
    const int bbase = 16384 + wn*4096 + colrow*32 + swz;    // + j*1024 + h*512
    const int NT = kd >> 6;

    f32x4 acc[8][4];
    #pragma unroll
    for (int i=0;i<8;i++)
        #pragma unroll
        for (int j=0;j<4;j++) acc[i][j] = (f32x4){0.f,0.f,0.f,0.f};

    short8 aF[4], bF[4];

#define STG64(bufv, k0v, qv) do { \
    int flat = (qv)*8 + w; \
    int side = flat >> 5; \
    int idx = flat & 31; \
    int rowblk = idx >> 1, kc = idx & 1; \
    const unsigned short* g = planes + (size_t)side*PS \
        + (size_t)(((side ? mblk : lblk) << 8) + rowblk*16 + (lane>>2))*kd \
        + (size_t)(k0v) + kc*32 + (lane&3)*8; \
    unsigned short* lp = (unsigned short*)&lds[(bufv)*32768 + side*16384 + (rowblk*2+kc)*512]; \
    GLOAD16(g, lp); \
} while(0)

#define RDB64(bufv, h) do { \
    _Pragma("unroll") \
    for (int j=0;j<4;j++) \
        bF[j] = *(const short8*)&lds[(bufv)*32768 + bbase + j*1024 + (h)*512]; \
} while(0)

#define RDA64(bufv, h, ig) do { \
    _Pragma("unroll") \
    for (int ii=0;ii<4;ii++) \
        aF[ii] = *(const short8*)&lds[(bufv)*32768 + abase + ((ig)*4+ii)*1024 + (h)*512]; \
} while(0)

#define MMQ(ig) do { \
    __builtin_amdgcn_s_setprio(1); \
    _Pragma("unroll") \
    for (int ii=0;ii<4;ii++) \
        _Pragma("unroll") \
        for (int j=0;j<4;j++) \
            acc[(ig)*4+ii][j] = __builtin_amdgcn_mfma_f32_16x16x32_bf16( \
                                    aF[ii], bF[j], acc[(ig)*4+ii][j],0,0,0); \
    __builtin_amdgcn_s_setprio(0); \
} while(0)

    // prologue: stage tile 0 (8 loads/thread in flight)
    STG64(0,0,0); STG64(0,0,1); STG64(0,0,2); STG64(0,0,3);
    STG64(0,0,4); STG64(0,0,5); STG64(0,0,6); STG64(0,0,7);

    int cur = 0;
    for (int kt = 0; kt < NT-1; kt++){
        const int k0n = (kt+1) << 6;
        STG64(cur^1, k0n, 0); STG64(cur^1, k0n, 1);
        asm volatile("s_waitcnt vmcnt(2)" ::: "memory");
        barx();                           // current tile resident for all waves
        RDB64(cur,0); RDA64(cur,0,0);
        MMQ(0);
        STG64(cur^1, k0n, 2); STG64(cur^1, k0n, 3);
        RDA64(cur,0,1);
        MMQ(1);
        STG64(cur^1, k0n, 4); STG64(cur^1, k0n, 5);
        RDB64(cur,1); RDA64(cur,1,0);
        MMQ(0);
        STG64(cur^1, k0n, 6); STG64(cur^1, k0n, 7);
        RDA64(cur,1,1);
        MMQ(1);
        barx();                           // reads of buf[cur] done before reuse
        cur ^= 1;
    }
    asm volatile("s_waitcnt vmcnt(0)" ::: "memory");
    barx();
    RDB64(cur,0); RDA64(cur,0,0); MMQ(0);
    RDA64(cur,0,1); MMQ(1);
    RDB64(cur,1); RDA64(cur,1,0); MMQ(0);
    RDA64(cur,1,1); MMQ(1);

#undef STG64
#undef RDB64
#undef RDA64
#undef MMQ

    // ---- fused score + per-m max/argmax over this block's 256 l ----
    const int lbase = (lblk<<8) + wm*128;
    const int mbase = (mblk<<8) + wn*64;
    constexpr int D = lev_D(LEV);
    const float mval = ws[200+LEV];
    const float Dm2 = (float)D * mval * mval;
    const float* Pv  = ws + p_off(LEV)    + b*4096;
    const float* NIv = ws + ninv_off(LEV) + b*4096;
    const float* CSv = ws + csum_off(LEV) + b*4096;
    barx();                               // safe to reuse LDS
    float* smax = (float*)lds;                 // [2][256]
    int*   sarg = (int*)((char*)lds + 2048);   // [2][256]
    #pragma unroll
    for (int j=0;j<4;j++){
        int m = mbase + j*16 + colrow;
        float nv = NIv[m];
        float cmv = -mval*nv*CSv[m] + Dm2;
        float v = -FLT_MAX; int vi = 0x7fffffff;
        #pragma unroll
        for (int i=0;i<8;i++){
            #pragma unroll
            for (int rg=0; rg<4; rg++){
                int l = lbase + i*16 + rgrp*4 + rg;
                float sc = nv*acc[i][j][rg] - mval*Pv[l] + cmv;
                if (sc > v){ v = sc; vi = l; }
            }
        }
        #pragma unroll
        for (int off=16; off<64; off<<=1){
            float ov = __shfl_xor(v, off);
            int   oi = __shfl_xor(vi, off);
            if (ov > v || (ov == v && oi < vi)){ v = ov; vi = oi; }
        }
        if (rgrp == 0){
            smax[wm*256 + wn*64 + j*16 + colrow] = v;
            sarg[wm*256 + wn*64 + j*16 + colrow] = vi;
        }
    }
    barx();
    if (tid < 256){
        float v0 = smax[tid];     int a0 = sarg[tid];
        float v1 = smax[256+tid]; int a1 = sarg[256+tid];
        if (v1 > v0 || (v1 == v0 && a1 < a0)){ v0 = v1; a0 = a1; }
        int o = (b*32 + lblk)*4096 + (mblk<<8) + tid;
        ws[pmax_off(LEV) + o] = v0;
        ((int*)ws)[parg_off(LEV) + o] = a0;
    }
}

// ===========================================================================
// 256^2 BK=32 counted-vmcnt GEMM, NSP planes/side (chunked fallback only).
// MODE 1: G = acc. MODE 2: G += acc.
// ===========================================================================
template<int LEV, int MODE, int NSP>
__launch_bounds__(512, 2)
__global__ void k_g8(const unsigned short* __restrict__ planes0,
                     float* __restrict__ ws, float* __restrict__ G,
                     int b0, int kd, size_t bstride){
    const size_t PS = (size_t)4096 * kd;
    const unsigned short* planes = planes0 + (size_t)blockIdx.z * bstride;
    __shared__ unsigned short lds[2*2*NSP*256*32];
    const int tid = threadIdx.x;
    const int w = tid >> 6, lane = tid & 63;
    const int mblk = blockIdx.x, lblk = blockIdx.y;
    const int wm = w >> 2, wn = w & 3;
    const int colrow = lane & 15, rgrp = lane >> 4;
    const int swz = (rgrp ^ ((lane >> 1) & 3)) * 8;
    const int abase = wm*4096 + colrow*32 + swz;
    const int bbase = NSP*8192 + wn*2048 + colrow*32 + swz;
    const int NT = kd >> 5;
    const int BUFS = 2*NSP*8192;

    f32x4 acc[8][4];
    #pragma unroll
    for (int i=0;i<8;i++)
        #pragma unroll
        for (int j=0;j<4;j++) acc[i][j] = (f32x4){0.f,0.f,0.f,0.f};

    short8 aF[NSP][4], bF[NSP][4];

#define STAGE(bufv, k0v, qi) do { \
    _Pragma("unroll") \
    for (int e=0;e<NSP;e++){ \
        int flat = w*(4*NSP) + (qi)*NSP + e; \
        int p = flat >> 4; \
        int rb = (flat & 15) << 4; \
        int rowbase = (p < NSP ? lblk : mblk) << 8; \
        const unsigned short* g = planes + (size_t)p*PS \
            + (size_t)(rowbase + rb + (lane>>2))*kd + (size_t)(k0v) + (lane&3)*8; \
        unsigned short* lp = (unsigned short*)&lds[(bufv)*BUFS + p*8192 + rb*32]; \
        GLOAD16(g, lp); \
    } \
} while(0)

#define RDA(bufv, half) do { \
    _Pragma("unroll") \
    for (int pl=0; pl<NSP; pl++) \
        _Pragma("unroll") \
        for (int i=0;i<4;i++) \
            aF[pl][i] = *(const short8*)&lds[(bufv)*BUFS + pl*8192 + abase + ((half)*4+i)*512]; \
} while(0)

#define RDB(bufv, half) do { \
    _Pragma("unroll") \
    for (int pl=0; pl<NSP; pl++) \
        _Pragma("unroll") \
        for (int j=0;j<2;j++) \
            bF[pl][(half)*2+j] = *(const short8*)&lds[(bufv)*BUFS + pl*8192 + bbase + ((half)*2+j)*512]; \
} while(0)

#define MM(ihalf, jhalf) do { \
    __builtin_amdgcn_s_setprio(1); \
    _Pragma("unroll") \
    for (int i=0;i<4;i++) \
        _Pragma("unroll") \
        for (int j=0;j<2;j++){ \
            const int ai = (ihalf)*4+i, bj = (jhalf)*2+j; \
            acc[ai][bj] = __builtin_amdgcn_mfma_f32_16x16x32_bf16(aF[0][i], bF[0][bj], acc[ai][bj],0,0,0); \
            if (NSP>=2){ \
                acc[ai][bj] = __builtin_amdgcn_mfma_f32_16x16x32_bf16(aF[0][i], bF[1][bj], acc[ai][bj],0,0,0); \
                acc[ai][bj] = __builtin_amdgcn_mfma_f32_16x16x32_bf16(aF[1][i], bF[0][bj], acc[ai][bj],0,0,0); \
            } \
        } \
    __builtin_amdgcn_s_setprio(0); \
} while(0)

    STAGE(0, 0, 0); STAGE(0, 0, 1); STAGE(0, 0, 2); STAGE(0, 0, 3);

    int cur = 0;
    for (int kt = 0; kt < NT-1; kt++){
        const int k0n = (kt+1) << 5;
        STAGE(cur^1, k0n, 0);
        if constexpr (NSP==1) asm volatile("s_waitcnt vmcnt(1)" ::: "memory");
        else                  asm volatile("s_waitcnt vmcnt(2)" ::: "memory");
        barx();
        RDB(cur, 0); RDA(cur, 0);
        MM(0, 0);
        STAGE(cur^1, k0n, 1);
        RDB(cur, 1);
        MM(0, 1);
        STAGE(cur^1, k0n, 2);
        RDA(cur, 1);
        MM(1, 1);
        STAGE(cur^1, k0n, 3);
        MM(1, 0);
        barx();
        cur ^= 1;
    }
    asm volatile("s_waitcnt vmcnt(0)" ::: "memory");
    barx();
    RDB(cur, 0); RDA(cur, 0); MM(0, 0);
    RDB(cur, 1); MM(0, 1);
    RDA(cur, 1); MM(1, 1);
    MM(1, 0);

#undef STAGE
#undef RDA
#undef RDB
#undef MM

    const int lbase = (lblk<<8) + wm*128;
    const int mbase = (mblk<<8) + wn*64;

    #pragma unroll
    for (int i=0;i<8;i++){
        #pragma unroll
        for (int rg=0; rg<4; rg++){
            float* gp = G + (size_t)(lbase + i*16 + rgrp*4 + rg)*4096 + mbase + colrow;
            #pragma unroll
            for (int j=0;j<4;j++){
                float v = acc[i][j][rg];
                if (MODE == 2) v += gp[j*16];
                gp[j*16] = v;
            }
        }
    }
}

// --- OLD 128^2 MFMA GEMM (fallback for lev0 if ws too small) ---
template<int LEV, int MODE, int NSP>
__launch_bounds__(256, 2)
__global__ void k_gmfma(const unsigned short* __restrict__ planes,
                        float* __restrict__ ws, float* __restrict__ G,
                        int b, int kd){
    const size_t PS = (size_t)4096 * kd;
    __shared__ unsigned short lds[2*NSP*128*32];
    const int tid = threadIdx.x;
    const int w = tid >> 6, lane = tid & 63;
    const int mblk = blockIdx.x, lblk = blockIdx.y;
    const int lw = w >> 1, mw = w & 1;

    f32x4 acc[4][4];
    #pragma unroll
    for (int i=0;i<4;i++)
        #pragma unroll
        for (int j=0;j<4;j++) acc[i][j] = (f32x4){0.f,0.f,0.f,0.f};

    const int srow = lane >> 2, ssl = lane & 3;
    const int colrow = lane & 15, kk = lane >> 4;
    const int swz = (kk ^ ((lane >> 1) & 3)) * 8;
    const int aRow0 = lw*64 + colrow;
    const int bRow0 = mw*64 + colrow;

    for (int k0 = 0; k0 < kd; k0 += 32){
        #pragma unroll
        for (int p = 0; p < 2*NSP; p++){
            const int rb = (p < NSP ? lblk : mblk)*128 + w*32 + srow;
            const unsigned short* gp0 = planes + (size_t)p*PS
                                        + (size_t)rb*kd + (size_t)k0 + ssl*8;
            unsigned short* lp0 = &lds[p*4096 + w*1024];
            GLOAD16(gp0, lp0);
            GLOAD16(gp0 + (size_t)16*kd, lp0 + 512);
        }
        __syncthreads();

        short8 aF[NSP][4];
        #pragma unroll
        for (int pa=0; pa<NSP; pa++)
            #pragma unroll
            for (int i=0;i<4;i++)
                aF[pa][i] = *(const short8*)&lds[pa*4096 + (aRow0 + i*16)*32 + swz];
        #pragma unroll
        for (int pb=0; pb<NSP; pb++){
            short8 bF[4];
            #pragma unroll
            for (int j=0;j<4;j++)
                bF[j] = *(const short8*)&lds[(NSP+pb)*4096 + (bRow0 + j*16)*32 + swz];
            const int npa = NSP - pb;
            for (int pa=0; pa<npa; pa++)
                #pragma unroll
                for (int i=0;i<4;i++)
                    #pragma unroll
                    for (int j=0;j<4;j++)
                        acc[i][j] = __builtin_amdgcn_mfma_f32_16x16x32_bf16(
                                        aF[pa][i], bF[j], acc[i][j], 0, 0, 0);
        }
        __syncthreads();
    }

    const int lbase = lblk*128 + lw*64;
    const int mbase = mblk*128 + mw*64;
    const int rgrp = lane >> 4;

    if (MODE != 0){
        #pragma unroll
        for (int i=0;i<4;i++){
            #pragma unroll
            for (int rg=0; rg<4; rg++){
                float* gp = G + (size_t)(lbase + i*16 + rgrp*4 + rg)*4096
                              + mbase + colrow;
                #pragma unroll
                for (int j=0;j<4;j++){
                    float v = acc[i][j][rg];
                    if (MODE == 2) v += gp[j*16];
                    gp[j*16] = v;
                }
            }
        }
        return;
    }

    constexpr int D = lev_D(LEV);
    const float mval = ws[200+LEV];
    const float Dm2 = (float)D * mval * mval;
    const float* Pv  = ws + p_off(LEV)    + b*4096;
    const float* NIv = ws + ninv_off(LEV) + b*4096;
    const float* CSv = ws + csum_off(LEV) + b*4096;
    float* smax = (float*)lds;
    int*   sarg = (int*)&lds[512];
    #pragma unroll
    for (int j=0;j<4;j++){
        int m = mbase + j*16 + colrow;
        float nv = NIv[m];
        float cmv = -mval*nv*CSv[m] + Dm2;
        float v = -FLT_MAX; int vi = 0x7fffffff;
        #pragma unroll
        for (int i=0;i<4;i++){
            #pragma unroll
            for (int rg=0; rg<4; rg++){
                int l = lbase + i*16 + rgrp*4 + rg;
                float sc = nv*acc[i][j][rg] - mval*Pv[l] + cmv;
                if (sc > v){ v = sc; vi = l; }
            }
        }
        #pragma unroll
        for (int off=16; off<64; off<<=1){
            float ov = __shfl_xor(v, off);
            int   oi = __shfl_xor(vi, off);
            if (ov > v || (ov == v && oi < vi)){ v = ov; vi = oi; }
        }
        if (rgrp == 0){
            smax[w*64 + j*16 + colrow] = v;
            sarg[w*64 + j*16 + colrow] = vi;
        }
    }
    __syncthreads();
    if (tid < 128){
        int mg = tid >> 6, idx = tid & 63;
        float v0 = smax[mg*64 + idx];     int a0 = sarg[mg*64 + idx];
        float v1 = smax[(mg+2)*64 + idx]; int a1 = sarg[(mg+2)*64 + idx];
        if (v1 > v0 || (v1 == v0 && a1 < a0)){ v0 = v1; a0 = a1; }
        int m = mblk*128 + mg*64 + idx;
        int o = (b*32 + lblk)*4096 + m;
        ws[pmax_off(LEV) + o] = v0;
        ((int*)ws)[parg_off(LEV) + o] = a0;
    }
}

// --- score + max/argmax from accumulated G; grid (64 mblk, 8 lsplit) ---
template<int LEV>
__global__ void k_score(const float* __restrict__ G, float* __restrict__ ws, int b){
    constexpr int D = lev_D(LEV);
    __shared__ float smax[4][64];
    __shared__ int   sarg[4][64];
    int tid = threadIdx.x, mloc = tid & 63, r = tid >> 6;
    int m = blockIdx.x*64 + mloc;
    int l0 = blockIdx.y*512;
    float mval = ws[200+LEV];
    float nv = ws[ninv_off(LEV) + b*4096 + m];
    float cmv = -mval*nv*ws[csum_off(LEV) + b*4096 + m] + (float)D*mval*mval;
    const float* Pv = ws + p_off(LEV) + b*4096;
    float best = -FLT_MAX; int bi = 0x7fffffff;
    for (int lt=0; lt<128; lt++){
        int l = l0 + lt*4 + r;
        float sc = nv*G[(size_t)l*4096 + m] - mval*Pv[l] + cmv;
        if (sc > best){ best = sc; bi = l; }
    }
    smax[r][mloc] = best; sarg[r][mloc] = bi;
    __syncthreads();
    if (tid < 64){
        float v = smax[0][tid]; int vi = sarg[0][tid];
        #pragma unroll
        for (int rr=1; rr<4; rr++){
            float ov = smax[rr][tid]; int oi = sarg[rr][tid];
            if (ov > v || (ov == v && oi < vi)){ v = ov; vi = oi; }
        }
        int o = (b*32 + blockIdx.y)*4096 + blockIdx.x*64 + tid;
        ws[pmax_off(LEV) + o] = v;
        ((int*)ws)[parg_off(LEV) + o] = vi;
    }
}

// --- reduce l-chunks -> S3,S2,S1,arg outputs (applies late scale) ---
__global__ void k_smax(float* __restrict__ ws, float* __restrict__ out,
                       int nch0, int nch1, int nch2){
    int gid = blockIdx.x*256 + threadIdx.x;
    if (gid >= 8192) return;
    int b = gid >> 12, m = gid & 4095;
    int nchs[3] = {nch0, nch1, nch2};
    for (int lev=0; lev<3; lev++){
        float mv = -FLT_MAX; int ma = 0x7fffffff;
        for (int ch=0; ch<nchs[lev]; ch++){
            int o = ((b*32+ch)<<12) + m;
            float v = ws[pmax_off(lev) + o];
            int   a = ((const int*)ws)[parg_off(lev) + o];
            if (v > mv || (v == mv && a < ma)){ mv=v; ma=a; }
        }
        out[lev*8192 + gid] = mv * ws[204+lev];
        if (lev==0){
            out[3*8192 + gid] = (float)ma;
            ((int*)ws)[arg_off() + gid] = ma;
        }
    }
}

// --- T = fold(gather(unfold(ref), arg)) / 9 ---
template<int LEV>
__global__ void k_transfer(const float* __restrict__ ref, const float* __restrict__ wsf,
                           float* __restrict__ outT){
    constexpr int C=LT<LEV>::C, H=LT<LEV>::H, K=LT<LEV>::K, S=LT<LEV>::S, PD=LT<LEV>::P;
    const int* arg = (const int*)wsf + arg_off();
    size_t gid = (size_t)blockIdx.x*256 + threadIdx.x;
    size_t total = (size_t)2*C*H*H;
    if (gid >= total) return;
    int x = (int)(gid % H);
    int y = (int)((gid / H) % H);
    int c = (int)((gid / ((size_t)H*H)) % C);
    int b = (int)(gid / ((size_t)C*H*H));
    const float* rimg = ref + (size_t)(b*C+c)*H*H;
    int byo = (y+PD)/S, ryo = (y+PD)%S;
    int bxo = (x+PD)/S, rxo = (x+PD)%S;
    float acc = 0.f;
    #pragma unroll
    for (int jy=0; jy<3; jy++){
        int ho = byo - jy;
        if (ho < 0 || ho >= 64) continue;
        int ki = ryo + jy*S;
        #pragma unroll
        for (int jx=0; jx<3; jx++){
            int wo = bxo - jx;
            if (wo < 0 || wo >= 64) continue;
            int kj = rxo + jx*S;
            int l = arg[b*4096 + ho*64 + wo];
            int ly = l>>6, lx = l&63;
            int srow = ly*S + ki - PD, scol = lx*S + kj - PD;
            if (srow>=0 && srow<H && scol>=0 && scol<H)
                acc += rimg[srow*H + scol];
        }
    }
    outT[gid] = acc * (1.0f/9.0f);
}

// --- lev0: bf16x3, k_g0 both-batch path (fallback: per-batch k_gmfma) ---
static void run_level0(const float* refsr, const float* lrsr, float* ws,
                       size_t ws_size, hipStream_t stream, int* nch){
    constexpr int D = 2304;
    const size_t PS = (size_t)4096 * D;
    k_rownorm<0><<<D/2, 256, 0, stream>>>(refsr, ws);
    k_scalar_early<0><<<1, 64, 0, stream>>>(ws);

    unsigned short* pl = (unsigned short*)((char*)ws + G_BASE_BYTES);
    if (ws_size >= G_BASE_BYTES + (size_t)2*6*PS*2){          // 234.5 MB
        nch[0] = 16;
        for (int b=0; b<2; b++){
            unsigned short* plb = pl + (size_t)b*6*PS;
            k_splitf<0,true ,3><<<4096, 256, 0, stream>>>(refsr, ws, plb,
                ws + p_off(0), nullptr, b, 0, D, 1);
            k_splitf<0,false,3><<<4096, 256, 0, stream>>>(lrsr, ws, plb + 3*PS,
                ws + csum_off(0), ws + ninv_off(0), b, 0, D, 1);
        }
        k_levfin<0><<<dim3(16,2), 256, 0, stream>>>(ws, 0);
        k_g0<<<dim3(32,16,2), 512, 0, stream>>>(pl, ws, D);
    } else {                                                   // per-batch fallback
        nch[0] = 32;
        for (int b=0; b<2; b++){
            k_splitf<0,true ,3><<<4096, 256, 0, stream>>>(refsr, ws, pl,
                ws + p_off(0), nullptr, b, 0, D, 1);
            k_splitf<0,false,3><<<4096, 256, 0, stream>>>(lrsr, ws, pl + 3*PS,
                ws + csum_off(0), ws + ninv_off(0), b, 0, D, 1);
            k_levfin<0><<<dim3(16,1), 256, 0, stream>>>(ws, b);
            k_gmfma<0,0,3><<<dim3(32,32), 256, 0, stream>>>(pl, ws, nullptr, b, D);
        }
    }
}

// --- lev1/lev2: NSP=1 BK=64 k_g8_64 (both-batch if fits; else per-batch) ---
template<int LEV>
static void run_level(const float* refsr, const float* lrsr, float* ws,
                      size_t ws_size, hipStream_t stream, int* nch){
    constexpr int D = lev_D(LEV);
    constexpr int NSP = 1;
    k_rownorm<LEV><<<D/2, 256, 0, stream>>>(refsr, ws);
    k_scalar_early<LEV><<<1, 64, 0, stream>>>(ws);

    const size_t PS = (size_t)4096 * D;
    const size_t perBatchBytes = (size_t)2*NSP*PS*2;   // both sides, one batch
    unsigned short* pl = (unsigned short*)((char*)ws + G_BASE_BYTES);
    float* G = ws + (G_BASE_BYTES >> 2);

    if (ws_size >= G_BASE_BYTES + 2*perBatchBytes){
        nch[LEV] = 16;
        for (int b=0; b<2; b++){
            unsigned short* plb = pl + (size_t)b*2*NSP*PS;
            k_splitf<LEV,true ,NSP><<<4096, 256, 0, stream>>>(refsr, ws, plb,
                ws + p_off(LEV), nullptr, b, 0, D, 1);
            k_splitf<LEV,false,NSP><<<4096, 256, 0, stream>>>(lrsr, ws, plb + NSP*PS,
                ws + csum_off(LEV), ws + ninv_off(LEV), b, 0, D, 1);
        }
        k_levfin<LEV><<<dim3(16,2), 256, 0, stream>>>(ws, 0);
        k_g8_64<LEV><<<dim3(16,16,2), 512, 0, stream>>>(pl, ws, 0, D, 2*NSP*PS);
        return;
    }

    bool fused = (ws_size >= G_BASE_BYTES + perBatchBytes);
    int kd = D;
    if (!fused){
        kd = 0;
        for (int div = 2; div <= 16; div <<= 1){
            if (ws_size >= CHUNK_PLANE_BYTES + (size_t)2*NSP*4096*(D/div)*2){ kd = D/div; break; }
        }
        if (!kd) kd = D/16;
        pl = (unsigned short*)((char*)ws + CHUNK_PLANE_BYTES);
    }
    const size_t PSc = (size_t)4096 * kd;
    const int nkc = D / kd;
    nch[LEV] = fused ? 16 : 8;

    for (int b=0; b<2; b++){
        for (int kc=0; kc<nkc; kc++){
            k_splitf<LEV,true ,NSP><<<4096, 256, 0, stream>>>(refsr, ws, pl,
                ws + p_off(LEV), nullptr, b, kc*kd, kd, kc==0);
            k_splitf<LEV,false,NSP><<<4096, 256, 0, stream>>>(lrsr, ws, pl + NSP*PSc,
                ws + csum_off(LEV), ws + ninv_off(LEV), b, kc*kd, kd, kc==0);
            if (!fused){
                if (kc==0) k_g8<LEV,1,NSP><<<dim3(16,16,1), 512, 0, stream>>>(pl, ws, G, b, kd, 0);
                else       k_g8<LEV,2,NSP><<<dim3(16,16,1), 512, 0, stream>>>(pl, ws, G, b, kd, 0);
            }
        }
        k_levfin<LEV><<<dim3(16,1), 256, 0, stream>>>(ws, b);
        if (fused) k_g8_64<LEV><<<dim3(16,16,1), 512, 0, stream>>>(pl, ws, b, kd, 0);
        else       k_score<LEV><<<dim3(64,8), 256, 0, stream>>>(G, ws, b);
    }
}

extern "C" void kernel_launch(void* const* d_in, const int* in_sizes, int n_in,
                              void* d_out, int out_size, void* d_ws, size_t ws_size,
                              hipStream_t stream){
    const float* lrsr[3]  = { (const float*)d_in[2], (const float*)d_in[1], (const float*)d_in[0] };
    const float* refsr[3] = { (const float*)d_in[5], (const float*)d_in[4], (const float*)d_in[3] };
    const float* refp[3]  = { (const float*)d_in[8], (const float*)d_in[7], (const float*)d_in[6] };
    float* ws  = (float*)d_ws;
    float* out = (float*)d_out;

    hipMemsetAsync(d_ws, 0, 4096, stream);  // zero scalar slots + scalars

    int nch[3];
    run_level0  (refsr[0], lrsr[0], ws, ws_size, stream, nch);
    run_level<1>(refsr[1], lrsr[1], ws, ws_size, stream, nch);
    run_level<2>(refsr[2], lrsr[2], ws, ws_size, stream, nch);

    k_scalar_late_all<<<1, 64, 0, stream>>>(ws);

    k_smax<<<32, 256, 0, stream>>>(ws, out, nch[0], nch[1], nch[2]);

    k_transfer<0><<< (2*256*64*64)/256,   256, 0, stream>>>(refp[0], ws, out + 32768);
    k_transfer<1><<< (2*128*128*128)/256, 256, 0, stream>>>(refp[1], ws, out + 2129920);
    k_transfer<2><<< (2*64*256*256)/256,  256, 0, stream>>>(refp[2], ws, out + 6324224);
}

// Round 13
// 2581.967 us; speedup vs baseline: 1.1228x; 1.1228x over previous
//
#include <hip/hip_runtime.h>
#include <cfloat>

// ---------------------------------------------------------------------------
// SearchTransfer (TTSR): 3-level patch correlation + argmax + gather/fold.
// Levels: 0 = lv3 (C=256,H=64,k=3,s=1,p=1,D=2304)
//         1 = lv2 (C=128,H=128,k=6,s=2,p=2,D=4608)
//         2 = lv1 (C=64,H=256,k=12,s=4,p=4,D=9216)
//
// score(l,m) = ninv[m]*G[l,m] - mval*P[l] - mval*ninv[m]*csum[m] + D*mval^2
// lev0: bf16x3 split, 6 products (exact argmax chain), k_g0 256x128
//       counted-vmcnt schedule, both batches one dispatch.
// lev1/2: single bf16 (NSP=1), 1 product, 256^2 BK=64 counted-vmcnt k_g8_64.
// k_splitf2: wave-per-row fused split+stats, sides+batches in one dispatch.
// ---------------------------------------------------------------------------

typedef short short8 __attribute__((ext_vector_type(8)));
typedef float f32x4  __attribute__((ext_vector_type(4)));

template<int LEV> struct LT;
template<> struct LT<0> { static constexpr int C=256, H=64,  K=3,  S=1, P=1; };
template<> struct LT<1> { static constexpr int C=128, H=128, K=6,  S=2, P=2; };
template<> struct LT<2> { static constexpr int C=64,  H=256, K=12, S=4, P=4; };

__host__ __device__ constexpr int lev_D(int lev){ return lev==0?2304:(lev==1?4608:9216); }
// ws float-index offsets
// [0,192): scalar slots: lev*64 + q*16 + slot (q:0=sum_rs,1=ssq_rs,2=sum_lr,3=ssq_lr)
// 200+lev: mval  204+lev: scale  208: gy2_lev0  212+lev: gx2
__host__ __device__ constexpr int rho_off(int lev){ return 256 + (lev>0?2*2304:0) + (lev>1?2*4608:0); }
__host__ __device__ constexpr int p_off(int lev)   { return 32512  + lev*8192;   }
__host__ __device__ constexpr int ninv_off(int lev){ return 57088  + lev*8192;   }
__host__ __device__ constexpr int csum_off(int lev){ return 81664  + lev*8192;   }
__host__ __device__ constexpr int pmax_off(int lev){ return 106240 + lev*262144; }
__host__ __device__ constexpr int parg_off(int lev){ return 892672 + lev*262144; }
__host__ __device__ constexpr int arg_off(){ return 1679104; }
static constexpr size_t G_BASE_BYTES      = 8ull  << 20;
static constexpr size_t CHUNK_PLANE_BYTES = 72ull << 20;

__device__ inline unsigned short f2bf(float f){
    unsigned int u = __float_as_uint(f);
    return (unsigned short)((u + 0x7fffu + ((u >> 16) & 1u)) >> 16);
}
__device__ inline float bf2f(unsigned short h){ return __uint_as_float(((unsigned)h) << 16); }

#define GLOAD16(g, l) __builtin_amdgcn_global_load_lds( \
    (const __attribute__((address_space(1))) unsigned int*)(g), \
    (__attribute__((address_space(3))) unsigned int*)(l), 16, 0, 0)

__device__ __forceinline__ void barx(){
    __builtin_amdgcn_sched_barrier(0);
    __builtin_amdgcn_s_barrier();
    __builtin_amdgcn_sched_barrier(0);
}

// --- per-(b,d) row norm of refsr unfold + rs scalar slots ---
template<int LEV>
__global__ void k_rownorm(const float* __restrict__ refsr, float* __restrict__ ws){
    constexpr int C=LT<LEV>::C, H=LT<LEV>::H, K=LT<LEV>::K, S=LT<LEV>::S, PD=LT<LEV>::P;
    constexpr int D = C*K*K, KK=K*K;
    __shared__ float sh0[4], sh1[4];
    int tid = threadIdx.x, lane = tid & 63, w = tid >> 6;
    int wid = (blockIdx.x*blockDim.x + tid) >> 6;
    int b = wid / D, d = wid % D;
    int c = d/KK, rem = d%KK, ki = rem/K, kj = rem%K;
    const float* img = refsr + (size_t)(b*C + c)*H*H;
    float sum=0.f, ssq=0.f;
    for (int idx=lane; idx<4096; idx+=64){
        int ho=idx>>6, wo=idx&63;
        int row = ho*S+ki-PD, col = wo*S+kj-PD;
        if (row>=0 && row<H && col>=0 && col<H){
            float v = img[row*H+col]; sum += v; ssq += v*v;
        }
    }
    #pragma unroll
    for (int off=32; off; off>>=1){ sum += __shfl_xor(sum,off); ssq += __shfl_xor(ssq,off); }
    if (lane==0){
        float rinv = 1.0f / fmaxf(sqrtf(ssq), 1e-12f);
        ws[rho_off(LEV) + b*D + d] = rinv;
        sh0[w] = sum*rinv;
        sh1[w] = ssq*rinv*rinv;
    }
    __syncthreads();
    if (tid==0){
        int s = blockIdx.x & 15;
        atomicAdd(&ws[LEV*64 + 0*16 + s], sh0[0]+sh0[1]+sh0[2]+sh0[3]);
        atomicAdd(&ws[LEV*64 + 1*16 + s], sh1[0]+sh1[1]+sh1[2]+sh1[3]);
    }
}

template<int LEV>
__global__ void k_scalar_early(float* __restrict__ ws){
    if (threadIdx.x || blockIdx.x) return;
    float s0=0.f, s1=0.f;
    for (int s=0;s<16;s++){ s0 += ws[LEV*64+s]; s1 += ws[LEV*64+16+s]; }
    float BDL = 2.0f * (float)lev_D(LEV) * 4096.0f;
    float m = s0 / BDL;
    ws[200+LEV] = m;
    ws[212+LEV] = s1 - 2.f*m*s0 + BDL*m*m;
}

// --- MERGED fused split+stats: one WAVE per row l; side=blockIdx.y (0=rs
//     w/ rinv scaling -> P; 1=lr -> csum/ssq); batch=blockIdx.z (b=b0+z).
//     Planes at pl + z*bstride + side*NSP*PS. grid (1024, 2, nb), 256 thr. ---
template<int LEV, int NSP>
__global__ void k_splitf2(const float* __restrict__ refsr, const float* __restrict__ lrsr,
                          float* __restrict__ ws, unsigned short* __restrict__ pl,
                          size_t bstride, int b0, int kb0, int kd, int first){
    constexpr int C=LT<LEV>::C, H=LT<LEV>::H, K=LT<LEV>::K, S=LT<LEV>::S, PD=LT<LEV>::P;
    constexpr int KK=K*K;
    const size_t PS = (size_t)4096 * kd;
    const int side = blockIdx.y;
    const int bz = blockIdx.z, b = b0 + bz;
    const int tid = threadIdx.x, lane = tid & 63, w = tid >> 6;
    const int l = blockIdx.x*4 + w;
    const int ly = l>>6, lx = l&63;
    const float* img = (side==0 ? refsr : lrsr) + (size_t)b*C*H*H;
    unsigned short* base = pl + (size_t)bz*bstride + (size_t)side*NSP*PS;
    const float* rinv = ws + rho_off(LEV) + b*lev_D(LEV);
    const int kslots = kd >> 3;
    float sum = 0.f, ssq = 0.f;
    for (int si = lane; si < kslots; si += 64){
        int kl0 = si*8;
        unsigned short h[NSP][8];
        #pragma unroll
        for (int j=0;j<8;j++){
            int k = kb0 + kl0 + j; int c=k/KK, rem=k%KK, ki=rem/K, kj=rem%K;
            int row=ly*S+ki-PD, col=lx*S+kj-PD;
            float x = (row>=0 && row<H && col>=0 && col<H)
                      ? img[(size_t)(c*H+row)*H+col] : 0.f;
            if (side==0) x *= rinv[k];
            unsigned short a = f2bf(x); h[0][j]=a;
            float rec = bf2f(a);
            if (NSP>=2){
                float r = x - bf2f(a);
                unsigned short m = f2bf(r); h[1][j]=m;
                rec += bf2f(m);
                if (NSP==3){
                    float r2 = r - bf2f(m);
                    unsigned short c2 = f2bf(r2); h[2][j]=c2;
                    rec += bf2f(c2);
                }
            }
            sum += rec; ssq += rec*rec;
        }
        int slot = si & 3, sw = slot ^ ((l>>1)&3);
        size_t off = (size_t)l*kd + (size_t)(kl0 & ~31) + sw*8;
        #pragma unroll
        for (int q=0;q<NSP;q++){
            uint4 u;
            u.x=h[q][0]|((unsigned)h[q][1]<<16); u.y=h[q][2]|((unsigned)h[q][3]<<16);
            u.z=h[q][4]|((unsigned)h[q][5]<<16); u.w=h[q][6]|((unsigned)h[q][7]<<16);
            *(uint4*)(base + q*PS + off) = u;
        }
    }
    #pragma unroll
    for (int off=32; off; off>>=1){ sum += __shfl_xor(sum,off); ssq += __shfl_xor(ssq,off); }
    if (lane==0){
        int o = b*4096 + l;
        if (side==0){
            float* P = ws + p_off(LEV);
            if (first) P[o] = sum; else P[o] += sum;
        } else {
            float* CS = ws + csum_off(LEV);
            float* SQ = ws + ninv_off(LEV);
            if (first){ CS[o] = sum; SQ[o] = ssq; }
            else      { CS[o] += sum; SQ[o] += ssq; }
        }
    }
}

// --- per-(lev, b=b0+blockIdx.y): ssq -> ninv in place; lr scalar slots ---
template<int LEV>
__global__ void k_levfin(float* __restrict__ ws, int b0){
    __shared__ float r0[4], r1[4];
    int tid = threadIdx.x, lane = tid & 63, w = tid >> 6;
    int b = b0 + blockIdx.y;
    int m = blockIdx.x*256 + tid;
    float ssq = ws[ninv_off(LEV) + b*4096 + m];
    float ninv = 1.0f / fmaxf(sqrtf(ssq), 1e-12f);
    ws[ninv_off(LEV) + b*4096 + m] = ninv;
    float y0 = ws[csum_off(LEV) + b*4096 + m] * ninv;
    float y1 = ssq * ninv * ninv;
    #pragma unroll
    for (int off=32; off; off>>=1){ y0 += __shfl_xor(y0,off); y1 += __shfl_xor(y1,off); }
    if (lane==0){ r0[w]=y0; r1[w]=y1; }
    __syncthreads();
    if (tid==0){
        int s = blockIdx.x & 15;
        atomicAdd(&ws[LEV*64 + 2*16 + s], r0[0]+r0[1]+r0[2]+r0[3]);
        atomicAdd(&ws[LEV*64 + 3*16 + s], r1[0]+r1[1]+r1[2]+r1[3]);
    }
}

// --- all three levels' scales (preserves ym3 bug: lev1 uses lev0's gy2) ---
__global__ void k_scalar_late_all(float* __restrict__ ws){
    if (threadIdx.x || blockIdx.x) return;
    float gy2_0 = 0.f;
    for (int lev=0; lev<3; lev++){
        float s2=0.f, s3=0.f;
        for (int s=0;s<16;s++){ s2 += ws[lev*64+32+s]; s3 += ws[lev*64+48+s]; }
        float BDL = 2.0f * (float)lev_D(lev) * 4096.0f;
        float m = ws[200+lev];
        float gy2 = s3 - 2.f*m*s2 + BDL*m*m;
        if (lev==0) gy2_0 = gy2;
        float gx2 = ws[212+lev];
        float gyu = (lev==1) ? gy2_0 : gy2;
        ws[204+lev] = 1.0f/(sqrtf(gx2)*sqrtf(gyu));
    }
}

// ===========================================================================
// lev0 256(l)x128(m) counted-vmcnt GEMM, NSP=3 both sides (6 products),
// fused score/max/argmax. 512 thr, 144KB LDS, both batches via blockIdx.z.
// ===========================================================================
__launch_bounds__(512, 1)
__global__ void k_g0(const unsigned short* __restrict__ planes0,
                     float* __restrict__ ws, int kd){
    const size_t PS = (size_t)4096 * kd;
    const int b = blockIdx.z;
    const unsigned short* planes = planes0 + (size_t)b*6*PS;
    __shared__ unsigned short lds[2*36864];   // 144 KB
    const int tid = threadIdx.x;
    const int w = tid >> 6, lane = tid & 63;
    const int mblk = blockIdx.x, lblk = blockIdx.y;
    const int wm = w >> 2, wn = w & 3;
    const int colrow = lane & 15, rgrp = lane >> 4;
    const int swz = (rgrp ^ ((lane >> 1) & 3)) * 8;
    const int abase = wm*4096 + colrow*32 + swz;          // + p*8192 + i*512
    const int bbase = 24576 + wn*1024 + colrow*32 + swz;  // + p*4096 + j*512
    const int NT = kd >> 5;

    f32x4 acc[8][2];
    #pragma unroll
    for (int i=0;i<8;i++){ acc[i][0]=(f32x4){0,0,0,0}; acc[i][1]=(f32x4){0,0,0,0}; }

    short8 bF[3][2];

#define STAGE0(bufv, k0v, qv) do { \
    int f = w*9 + (qv); \
    int isA = f < 48; \
    int p  = isA ? (f>>4) : ((f-48)>>3); \
    int rb = isA ? ((f&15)<<4) : (((f-48)&7)<<4); \
    const unsigned short* g = planes + (size_t)(isA ? p : 3+p)*PS \
        + (size_t)((isA ? (lblk<<8) : (mblk<<7)) + rb + (lane>>2))*kd \
        + (size_t)(k0v) + (lane&3)*8; \
    unsigned short* lp = (unsigned short*)&lds[(bufv)*36864 \
        + (isA ? p*8192 : 24576 + p*4096) + rb*32]; \
    GLOAD16(g, lp); \
} while(0)

#define RDB0(bufv) do { \
    _Pragma("unroll") \
    for (int p=0;p<3;p++) \
        _Pragma("unroll") \
        for (int j=0;j<2;j++) \
            bF[p][j] = *(const short8*)&lds[(bufv)*36864 + bbase + p*4096 + j*512]; \
} while(0)

#define MMI(bufv, i) do { \
    short8 a0 = *(const short8*)&lds[(bufv)*36864 + 0*8192 + abase + (i)*512]; \
    short8 a1 = *(const short8*)&lds[(bufv)*36864 + 1*8192 + abase + (i)*512]; \
    short8 a2 = *(const short8*)&lds[(bufv)*36864 + 2*8192 + abase + (i)*512]; \
    __builtin_amdgcn_s_setprio(1); \
    _Pragma("unroll") \
    for (int j=0;j<2;j++){ \
        acc[i][j] = __builtin_amdgcn_mfma_f32_16x16x32_bf16(a0, bF[0][j], acc[i][j],0,0,0); \
        acc[i][j] = __builtin_amdgcn_mfma_f32_16x16x32_bf16(a0, bF[1][j], acc[i][j],0,0,0); \
        acc[i][j] = __builtin_amdgcn_mfma_f32_16x16x32_bf16(a1, bF[0][j], acc[i][j],0,0,0); \
        acc[i][j] = __builtin_amdgcn_mfma_f32_16x16x32_bf16(a0, bF[2][j], acc[i][j],0,0,0); \
        acc[i][j] = __builtin_amdgcn_mfma_f32_16x16x32_bf16(a1, bF[1][j], acc[i][j],0,0,0); \
        acc[i][j] = __builtin_amdgcn_mfma_f32_16x16x32_bf16(a2, bF[0][j], acc[i][j],0,0,0); \
    } \
    __builtin_amdgcn_s_setprio(0); \
} while(0)

    STAGE0(0,0,0); STAGE0(0,0,1); STAGE0(0,0,2); STAGE0(0,0,3); STAGE0(0,0,4);
    STAGE0(0,0,5); STAGE0(0,0,6); STAGE0(0,0,7); STAGE0(0,0,8);

    int cur = 0;
    for (int kt = 0; kt < NT-1; kt++){
        const int k0n = (kt+1) << 5;
        STAGE0(cur^1, k0n, 0); STAGE0(cur^1, k0n, 1); STAGE0(cur^1, k0n, 2);
        asm volatile("s_waitcnt vmcnt(3)" ::: "memory");
        barx();
        RDB0(cur);
        MMI(cur,0); MMI(cur,1);
        STAGE0(cur^1, k0n, 3); STAGE0(cur^1, k0n, 4); STAGE0(cur^1, k0n, 5);
        MMI(cur,2); MMI(cur,3); MMI(cur,4);
        STAGE0(cur^1, k0n, 6); STAGE0(cur^1, k0n, 7); STAGE0(cur^1, k0n, 8);
        MMI(cur,5); MMI(cur,6); MMI(cur,7);
        barx();
        cur ^= 1;
    }
    asm volatile("s_waitcnt vmcnt(0)" ::: "memory");
    barx();
    RDB0(cur);
    MMI(cur,0); MMI(cur,1); MMI(cur,2); MMI(cur,3);
    MMI(cur,4); MMI(cur,5); MMI(cur,6); MMI(cur,7);

#undef STAGE0
#undef RDB0
#undef MMI

    const int lbase = (lblk<<8) + wm*128;
    const int mbase = (mblk<<7) + wn*32;
    const int D = kd;
    const float mval = ws[200];
    const float Dm2 = (float)D * mval * mval;
    const float* Pv  = ws + p_off(0)    + b*4096;
    const float* NIv = ws + ninv_off(0) + b*4096;
    const float* CSv = ws + csum_off(0) + b*4096;
    barx();
    float* smax = (float*)lds;                 // [2][128]
    int*   sarg = (int*)((char*)lds + 1024);   // [2][128]
    #pragma unroll
    for (int j=0;j<2;j++){
        int m = mbase + j*16 + colrow;
        float nv = NIv[m];
        float cmv = -mval*nv*CSv[m] + Dm2;
        float v = -FLT_MAX; int vi = 0x7fffffff;
        #pragma unroll
        for (int i=0;i<8;i++){
            #pragma unroll
            for (int rg=0; rg<4; rg++){
                int l = lbase + i*16 + rgrp*4 + rg;
                float sc = nv*acc[i][j][rg] - mval*Pv[l] + cmv;
                if (sc > v){ v = sc; vi = l; }
            }
        }
        #pragma unroll
        for (int off=16; off<64; off<<=1){
            float ov = __shfl_xor(v, off);
            int   oi = __shfl_xor(vi, off);
            if (ov > v || (ov == v && oi < vi)){ v = ov; vi = oi; }
        }
        if (rgrp == 0){
            smax[wm*128 + wn*32 + j*16 + colrow] = v;
            sarg[wm*128 + wn*32 + j*16 + colrow] = vi;
        }
    }
    barx();
    if (tid < 128){
        float v0 = smax[tid];     int a0 = sarg[tid];
        float v1 = smax[128+tid]; int a1 = sarg[128+tid];
        if (v1 > v0 || (v1 == v0 && a1 < a0)){ v0 = v1; a0 = a1; }
        int o = (b*32 + lblk)*4096 + (mblk<<7) + tid;
        ws[pmax_off(0) + o] = v0;
        ((int*)ws)[parg_off(0) + o] = a0;
    }
}

// ===========================================================================
// NSP=1 256^2 BK=64 counted-vmcnt GEMM, fused score/max/argmax.
// 512 thr, 128KB LDS. b = b0 + blockIdx.z, per-batch plane stride bstride.
// ===========================================================================
template<int LEV>
__launch_bounds__(512, 1)
__global__ void k_g8_64(const unsigned short* __restrict__ planes0,
                        float* __restrict__ ws, int b0, int kd, size_t bstride){
    const size_t PS = (size_t)4096 * kd;
    const int b = b0 + blockIdx.z;
    const unsigned short* planes = planes0 + (size_t)blockIdx.z * bstride;
    __shared__ unsigned short lds[2*32768];   // 128 KB
    const int tid = threadIdx.x;
    const int w = tid >> 6, lane = tid & 63;
    const int mblk = blockIdx.x, lblk = blockIdx.y;
    const int wm = w >> 2, wn = w & 3;
    const int colrow = lane & 15, rgrp = lane >> 4;
    const int swz = (rgrp ^ ((lane >> 1) & 3)) * 8;
    const int abase = wm*8192 + colrow*32 + swz;            // + i*1024 + h*512
    const int bbase = 16384 + wn*4096 + colrow*32 + swz;    // + j*1024 + h*512
    const int NT = kd >> 6;

    f32x4 acc[8][4];
    #pragma unroll
    for (int i=0;i<8;i++)
        #pragma unroll
        for (int j=0;j<4;j++) acc[i][j] = (f32x4){0.f,0.f,0.f,0.f};

    short8 aF[4], bF[4];

#define STG64(bufv, k0v, qv) do { \
    int flat = (qv)*8 + w; \
    int side = flat >> 5; \
    int idx = flat & 31; \
    int rowblk = idx >> 1, kc = idx & 1; \
    const unsigned short* g = planes + (size_t)side*PS \
        + (size_t)(((side ? mblk : lblk) << 8) + rowblk*16 + (lane>>2))*kd \
        + (size_t)(k0v) + kc*32 + (lane&3)*8; \
    unsigned short* lp = (unsigned short*)&lds[(bufv)*32768 + side*16384 + (rowblk*2+kc)*512]; \
    GLOAD16(g, lp); \
} while(0)

#define RDB64(bufv, h) do { \
    _Pragma("unroll") \
    for (int j=0;j<4;j++) \
        bF[j] = *(const short8*)&lds[(bufv)*32768 + bbase + j*1024 + (h)*512]; \
} while(0)

#define RDA64(bufv, h, ig) do { \
    _Pragma("unroll") \
    for (int ii=0;ii<4;ii++) \
        aF[ii] = *(const short8*)&lds[(bufv)*32768 + abase + ((ig)*4+ii)*1024 + (h)*512]; \
} while(0)

#define MMQ(ig) do { \
    __builtin_amdgcn_s_setprio(1); \
    _Pragma("unroll") \
    for (int ii=0;ii<4;ii++) \
        _Pragma("unroll") \
        for (int j=0;j<4;j++) \
            acc[(ig)*4+ii][j] = __builtin_amdgcn_mfma_f32_16x16x32_bf16( \
                                    aF[ii], bF[j], acc[(ig)*4+ii][j],0,0,0); \
    __builtin_amdgcn_s_setprio(0); \
} while(0)

    STG64(0,0,0); STG64(0,0,1); STG64(0,0,2); STG64(0,0,3);
    STG64(0,0,4); STG64(0,0,5); STG64(0,0,6); STG64(0,0,7);

    int cur = 0;
    for (int kt = 0; kt < NT-1; kt++){
        const int k0n = (kt+1) << 6;
        STG64(cur^1, k0n, 0); STG64(cur^1, k0n, 1);
        asm volatile("s_waitcnt vmcnt(2)" ::: "memory");
        barx();
        RDB64(cur,0); RDA64(cur,0,0);
        MMQ(0);
        STG64(cur^1, k0n, 2); STG64(cur^1, k0n, 3);
        RDA64(cur,0,1);
        MMQ(1);
        STG64(cur^1, k0n, 4); STG64(cur^1, k0n, 5);
        RDB64(cur,1); RDA64(cur,1,0);
        MMQ(0);
        STG64(cur^1, k0n, 6); STG64(cur^1, k0n, 7);
        RDA64(cur,1,1);
        MMQ(1);
        barx();
        cur ^= 1;
    }
    asm volatile("s_waitcnt vmcnt(0)" ::: "memory");
    barx();
    RDB64(cur,0); RDA64(cur,0,0); MMQ(0);
    RDA64(cur,0,1); MMQ(1);
    RDB64(cur,1); RDA64(cur,1,0); MMQ(0);
    RDA64(cur,1,1); MMQ(1);

#undef STG64
#undef RDB64
#undef RDA64
#undef MMQ

    const int lbase = (lblk<<8) + wm*128;
    const int mbase = (mblk<<8) + wn*64;
    constexpr int D = lev_D(LEV);
    const float mval = ws[200+LEV];
    const float Dm2 = (float)D * mval * mval;
    const float* Pv  = ws + p_off(LEV)    + b*4096;
    const float* NIv = ws + ninv_off(LEV) + b*4096;
    const float* CSv = ws + csum_off(LEV) + b*4096;
    barx();
    float* smax = (float*)lds;                 // [2][256]
    int*   sarg = (int*)((char*)lds + 2048);   // [2][256]
    #pragma unroll
    for (int j=0;j<4;j++){
        int m = mbase + j*16 + colrow;
        float nv = NIv[m];
        float cmv = -mval*nv*CSv[m] + Dm2;
        float v = -FLT_MAX; int vi = 0x7fffffff;
        #pragma unroll
        for (int i=0;i<8;i++){
            #pragma unroll
            for (int rg=0; rg<4; rg++){
                int l = lbase + i*16 + rgrp*4 + rg;
                float sc = nv*acc[i][j][rg] - mval*Pv[l] + cmv;
                if (sc > v){ v = sc; vi = l; }
            }
        }
        #pragma unroll
        for (int off=16; off<64; off<<=1){
            float ov = __shfl_xor(v, off);
            int   oi = __shfl_xor(vi, off);
            if (ov > v || (ov == v && oi < vi)){ v = ov; vi = oi; }
        }
        if (rgrp == 0){
            smax[wm*256 + wn*64 + j*16 + colrow] = v;
            sarg[wm*256 + wn*64 + j*16 + colrow] = vi;
        }
    }
    barx();
    if (tid < 256){
        float v0 = smax[tid];     int a0 = sarg[tid];
        float v1 = smax[256+tid]; int a1 = sarg[256+tid];
        if (v1 > v0 || (v1 == v0 && a1 < a0)){ v0 = v1; a0 = a1; }
        int o = (b*32 + lblk)*4096 + (mblk<<8) + tid;
        ws[pmax_off(LEV) + o] = v0;
        ((int*)ws)[parg_off(LEV) + o] = a0;
    }
}

// ===========================================================================
// 256^2 BK=32 counted-vmcnt GEMM, NSP planes/side (chunked fallback only).
// MODE 1: G = acc. MODE 2: G += acc.
// ===========================================================================
template<int LEV, int MODE, int NSP>
__launch_bounds__(512, 2)
__global__ void k_g8(const unsigned short* __restrict__ planes0,
                     float* __restrict__ ws, float* __restrict__ G,
                     int b0, int kd, size_t bstride){
    const size_t PS = (size_t)4096 * kd;
    const unsigned short* planes = planes0 + (size_t)blockIdx.z * bstride;
    __shared__ unsigned short lds[2*2*NSP*256*32];
    const int tid = threadIdx.x;
    const int w = tid >> 6, lane = tid & 63;
    const int mblk = blockIdx.x, lblk = blockIdx.y;
    const int wm = w >> 2, wn = w & 3;
    const int colrow = lane & 15, rgrp = lane >> 4;
    const int swz = (rgrp ^ ((lane >> 1) & 3)) * 8;
    const int abase = wm*4096 + colrow*32 + swz;
    const int bbase = NSP*8192 + wn*2048 + colrow*32 + swz;
    const int NT = kd >> 5;
    const int BUFS = 2*NSP*8192;

    f32x4 acc[8][4];
    #pragma unroll
    for (int i=0;i<8;i++)
        #pragma unroll
        for (int j=0;j<4;j++) acc[i][j] = (f32x4){0.f,0.f,0.f,0.f};

    short8 aF[NSP][4], bF[NSP][4];

#define STAGE(bufv, k0v, qi) do { \
    _Pragma("unroll") \
    for (int e=0;e<NSP;e++){ \
        int flat = w*(4*NSP) + (qi)*NSP + e; \
        int p = flat >> 4; \
        int rb = (flat & 15) << 4; \
        int rowbase = (p < NSP ? lblk : mblk) << 8; \
        const unsigned short* g = planes + (size_t)p*PS \
            + (size_t)(rowbase + rb + (lane>>2))*kd + (size_t)(k0v) + (lane&3)*8; \
        unsigned short* lp = (unsigned short*)&lds[(bufv)*BUFS + p*8192 + rb*32]; \
        GLOAD16(g, lp); \
    } \
} while(0)

#define RDA(bufv, half) do { \
    _Pragma("unroll") \
    for (int pl=0; pl<NSP; pl++) \
        _Pragma("unroll") \
        for (int i=0;i<4;i++) \
            aF[pl][i] = *(const short8*)&lds[(bufv)*BUFS + pl*8192 + abase + ((half)*4+i)*512]; \
} while(0)

#define RDB(bufv, half) do { \
    _Pragma("unroll") \
    for (int pl=0; pl<NSP; pl++) \
        _Pragma("unroll") \
        for (int j=0;j<2;j++) \
            bF[pl][(half)*2+j] = *(const short8*)&lds[(bufv)*BUFS + pl*8192 + bbase + ((half)*2+j)*512]; \
} while(0)

#define MM(ihalf, jhalf) do { \
    __builtin_amdgcn_s_setprio(1); \
    _Pragma("unroll") \
    for (int i=0;i<4;i++) \
        _Pragma("unroll") \
        for (int j=0;j<2;j++){ \
            const int ai = (ihalf)*4+i, bj = (jhalf)*2+j; \
            acc[ai][bj] = __builtin_amdgcn_mfma_f32_16x16x32_bf16(aF[0][i], bF[0][bj], acc[ai][bj],0,0,0); \
            if (NSP>=2){ \
                acc[ai][bj] = __builtin_amdgcn_mfma_f32_16x16x32_bf16(aF[0][i], bF[1][bj], acc[ai][bj],0,0,0); \
                acc[ai][bj] = __builtin_amdgcn_mfma_f32_16x16x32_bf16(aF[1][i], bF[0][bj], acc[ai][bj],0,0,0); \
            } \
        } \
    __builtin_amdgcn_s_setprio(0); \
} while(0)

    STAGE(0, 0, 0); STAGE(0, 0, 1); STAGE(0, 0, 2); STAGE(0, 0, 3);

    int cur = 0;
    for (int kt = 0; kt < NT-1; kt++){
        const int k0n = (kt+1) << 5;
        STAGE(cur^1, k0n, 0);
        if constexpr (NSP==1) asm volatile("s_waitcnt vmcnt(1)" ::: "memory");
        else                  asm volatile("s_waitcnt vmcnt(2)" ::: "memory");
        barx();
        RDB(cur, 0); RDA(cur, 0);
        MM(0, 0);
        STAGE(cur^1, k0n, 1);
        RDB(cur, 1);
        MM(0, 1);
        STAGE(cur^1, k0n, 2);
        RDA(cur, 1);
        MM(1, 1);
        STAGE(cur^1, k0n, 3);
        MM(1, 0);
        barx();
        cur ^= 1;
    }
    asm volatile("s_waitcnt vmcnt(0)" ::: "memory");
    barx();
    RDB(cur, 0); RDA(cur, 0); MM(0, 0);
    RDB(cur, 1); MM(0, 1);
    RDA(cur, 1); MM(1, 1);
    MM(1, 0);

#undef STAGE
#undef RDA
#undef RDB
#undef MM

    const int lbase = (lblk<<8) + wm*128;
    const int mbase = (mblk<<8) + wn*64;

    #pragma unroll
    for (int i=0;i<8;i++){
        #pragma unroll
        for (int rg=0; rg<4; rg++){
            float* gp = G + (size_t)(lbase + i*16 + rgrp*4 + rg)*4096 + mbase + colrow;
            #pragma unroll
            for (int j=0;j<4;j++){
                float v = acc[i][j][rg];
                if (MODE == 2) v += gp[j*16];
                gp[j*16] = v;
            }
        }
    }
}

// --- OLD 128^2 MFMA GEMM (fallback for lev0 if ws too small) ---
template<int LEV, int MODE, int NSP>
__launch_bounds__(256, 2)
__global__ void k_gmfma(const unsigned short* __restrict__ planes,
                        float* __restrict__ ws, float* __restrict__ G,
                        int b, int kd){
    const size_t PS = (size_t)4096 * kd;
    __shared__ unsigned short lds[2*NSP*128*32];
    const int tid = threadIdx.x;
    const int w = tid >> 6, lane = tid & 63;
    const int mblk = blockIdx.x, lblk = blockIdx.y;
    const int lw = w >> 1, mw = w & 1;

    f32x4 acc[4][4];
    #pragma unroll
    for (int i=0;i<4;i++)
        #pragma unroll
        for (int j=0;j<4;j++) acc[i][j] = (f32x4){0.f,0.f,0.f,0.f};

    const int srow = lane >> 2, ssl = lane & 3;
    const int colrow = lane & 15, kk = lane >> 4;
    const int swz = (kk ^ ((lane >> 1) & 3)) * 8;
    const int aRow0 = lw*64 + colrow;
    const int bRow0 = mw*64 + colrow;

    for (int k0 = 0; k0 < kd; k0 += 32){
        #pragma unroll
        for (int p = 0; p < 2*NSP; p++){
            const int rb = (p < NSP ? lblk : mblk)*128 + w*32 + srow;
            const unsigned short* gp0 = planes + (size_t)p*PS
                                        + (size_t)rb*kd + (size_t)k0 + ssl*8;
            unsigned short* lp0 = &lds[p*4096 + w*1024];
            GLOAD16(gp0, lp0);
            GLOAD16(gp0 + (size_t)16*kd, lp0 + 512);
        }
        __syncthreads();

        short8 aF[NSP][4];
        #pragma unroll
        for (int pa=0; pa<NSP; pa++)
            #pragma unroll
            for (int i=0;i<4;i++)
                aF[pa][i] = *(const short8*)&lds[pa*4096 + (aRow0 + i*16)*32 + swz];
        #pragma unroll
        for (int pb=0; pb<NSP; pb++){
            short8 bF[4];
            #pragma unroll
            for (int j=0;j<4;j++)
                bF[j] = *(const short8*)&lds[(NSP+pb)*4096 + (bRow0 + j*16)*32 + swz];
            const int npa = NSP - pb;
            for (int pa=0; pa<npa; pa++)
                #pragma unroll
                for (int i=0;i<4;i++)
                    #pragma unroll
                    for (int j=0;j<4;j++)
                        acc[i][j] = __builtin_amdgcn_mfma_f32_16x16x32_bf16(
                                        aF[pa][i], bF[j], acc[i][j], 0, 0, 0);
        }
        __syncthreads();
    }

    const int lbase = lblk*128 + lw*64;
    const int mbase = mblk*128 + mw*64;
    const int rgrp = lane >> 4;

    if (MODE != 0){
        #pragma unroll
        for (int i=0;i<4;i++){
            #pragma unroll
            for (int rg=0; rg<4; rg++){
                float* gp = G + (size_t)(lbase + i*16 + rgrp*4 + rg)*4096
                              + mbase + colrow;
                #pragma unroll
                for (int j=0;j<4;j++){
                    float v = acc[i][j][rg];
                    if (MODE == 2) v += gp[j*16];
                    gp[j*16] = v;
                }
            }
        }
        return;
    }

    constexpr int D = lev_D(LEV);
    const float mval = ws[200+LEV];
    const float Dm2 = (float)D * mval * mval;
    const float* Pv  = ws + p_off(LEV)    + b*4096;
    const float* NIv = ws + ninv_off(LEV) + b*4096;
    const float* CSv = ws + csum_off(LEV) + b*4096;
    float* smax = (float*)lds;
    int*   sarg = (int*)&lds[512];
    #pragma unroll
    for (int j=0;j<4;j++){
        int m = mbase + j*16 + colrow;
        float nv = NIv[m];
        float cmv = -mval*nv*CSv[m] + Dm2;
        float v = -FLT_MAX; int vi = 0x7fffffff;
        #pragma unroll
        for (int i=0;i<4;i++){
            #pragma unroll
            for (int rg=0; rg<4; rg++){
                int l = lbase + i*16 + rgrp*4 + rg;
                float sc = nv*acc[i][j][rg] - mval*Pv[l] + cmv;
                if (sc > v){ v = sc; vi = l; }
            }
        }
        #pragma unroll
        for (int off=16; off<64; off<<=1){
            float ov = __shfl_xor(v, off);
            int   oi = __shfl_xor(vi, off);
            if (ov > v || (ov == v && oi < vi)){ v = ov; vi = oi; }
        }
        if (rgrp == 0){
            smax[w*64 + j*16 + colrow] = v;
            sarg[w*64 + j*16 + colrow] = vi;
        }
    }
    __syncthreads();
    if (tid < 128){
        int mg = tid >> 6, idx = tid & 63;
        float v0 = smax[mg*64 + idx];     int a0 = sarg[mg*64 + idx];
        float v1 = smax[(mg+2)*64 + idx]; int a1 = sarg[(mg+2)*64 + idx];
        if (v1 > v0 || (v1 == v0 && a1 < a0)){ v0 = v1; a0 = a1; }
        int m = mblk*128 + mg*64 + idx;
        int o = (b*32 + lblk)*4096 + m;
        ws[pmax_off(LEV) + o] = v0;
        ((int*)ws)[parg_off(LEV) + o] = a0;
    }
}

// --- score + max/argmax from accumulated G; grid (64 mblk, 8 lsplit) ---
template<int LEV>
__global__ void k_score(const float* __restrict__ G, float* __restrict__ ws, int b){
    constexpr int D = lev_D(LEV);
    __shared__ float smax[4][64];
    __shared__ int   sarg[4][64];
    int tid = threadIdx.x, mloc = tid & 63, r = tid >> 6;
    int m = blockIdx.x*64 + mloc;
    int l0 = blockIdx.y*512;
    float mval = ws[200+LEV];
    float nv = ws[ninv_off(LEV) + b*4096 + m];
    float cmv = -mval*nv*ws[csum_off(LEV) + b*4096 + m] + (float)D*mval*mval;
    const float* Pv = ws + p_off(LEV) + b*4096;
    float best = -FLT_MAX; int bi = 0x7fffffff;
    for (int lt=0; lt<128; lt++){
        int l = l0 + lt*4 + r;
        float sc = nv*G[(size_t)l*4096 + m] - mval*Pv[l] + cmv;
        if (sc > best){ best = sc; bi = l; }
    }
    smax[r][mloc] = best; sarg[r][mloc] = bi;
    __syncthreads();
    if (tid < 64){
        float v = smax[0][tid]; int vi = sarg[0][tid];
        #pragma unroll
        for (int rr=1; rr<4; rr++){
            float ov = smax[rr][tid]; int oi = sarg[rr][tid];
            if (ov > v || (ov == v && oi < vi)){ v = ov; vi = oi; }
        }
        int o = (b*32 + blockIdx.y)*4096 + blockIdx.x*64 + tid;
        ws[pmax_off(LEV) + o] = v;
        ((int*)ws)[parg_off(LEV) + o] = vi;
    }
}

// --- reduce l-chunks -> S3,S2,S1,arg outputs (applies late scale) ---
__global__ void k_smax(float* __restrict__ ws, float* __restrict__ out,
                       int nch0, int nch1, int nch2){
    int gid = blockIdx.x*256 + threadIdx.x;
    if (gid >= 8192) return;
    int b = gid >> 12, m = gid & 4095;
    int nchs[3] = {nch0, nch1, nch2};
    for (int lev=0; lev<3; lev++){
        float mv = -FLT_MAX; int ma = 0x7fffffff;
        for (int ch=0; ch<nchs[lev]; ch++){
            int o = ((b*32+ch)<<12) + m;
            float v = ws[pmax_off(lev) + o];
            int   a = ((const int*)ws)[parg_off(lev) + o];
            if (v > mv || (v == mv && a < ma)){ mv=v; ma=a; }
        }
        out[lev*8192 + gid] = mv * ws[204+lev];
        if (lev==0){
            out[3*8192 + gid] = (float)ma;
            ((int*)ws)[arg_off() + gid] = ma;
        }
    }
}

// --- T = fold(gather(unfold(ref), arg)) / 9 ; all 3 levels in one grid ---
template<int LEV>
__device__ __forceinline__ void transfer_body(int blk, const float* __restrict__ ref,
                                              const float* __restrict__ wsf,
                                              float* __restrict__ outT){
    constexpr int C=LT<LEV>::C, H=LT<LEV>::H, K=LT<LEV>::K, S=LT<LEV>::S, PD=LT<LEV>::P;
    const int* arg = (const int*)wsf + arg_off();
    size_t gid = (size_t)blk*256 + threadIdx.x;
    int x = (int)(gid % H);
    int y = (int)((gid / H) % H);
    int c = (int)((gid / ((size_t)H*H)) % C);
    int b = (int)(gid / ((size_t)C*H*H));
    const float* rimg = ref + (size_t)(b*C+c)*H*H;
    int byo = (y+PD)/S, ryo = (y+PD)%S;
    int bxo = (x+PD)/S, rxo = (x+PD)%S;
    float acc = 0.f;
    #pragma unroll
    for (int jy=0; jy<3; jy++){
        int ho = byo - jy;
        if (ho < 0 || ho >= 64) continue;
        int ki = ryo + jy*S;
        #pragma unroll
        for (int jx=0; jx<3; jx++){
            int wo = bxo - jx;
            if (wo < 0 || wo >= 64) continue;
            int kj = rxo + jx*S;
            int l = arg[b*4096 + ho*64 + wo];
            int ly = l>>6, lx = l&63;
            int srow = ly*S + ki - PD, scol = lx*S + kj - PD;
            if (srow>=0 && srow<H && scol>=0 && scol<H)
                acc += rimg[srow*H + scol];
        }
    }
    outT[gid] = acc * (1.0f/9.0f);
}

__global__ void k_transfer_all(const float* __restrict__ r0, const float* __restrict__ r1,
                               const float* __restrict__ r2, const float* __restrict__ wsf,
                               float* __restrict__ out){
    int blk = blockIdx.x;
    if (blk < 8192)       transfer_body<0>(blk,        r0, wsf, out + 32768);
    else if (blk < 24576) transfer_body<1>(blk-8192,   r1, wsf, out + 2129920);
    else                  transfer_body<2>(blk-24576,  r2, wsf, out + 6324224);
}

// --- lev0: bf16x3, k_g0 both-batch path (fallback: per-batch k_gmfma) ---
static void run_level0(const float* refsr, const float* lrsr, float* ws,
                       size_t ws_size, hipStream_t stream, int* nch){
    constexpr int D = 2304;
    const size_t PS = (size_t)4096 * D;
    k_rownorm<0><<<D/2, 256, 0, stream>>>(refsr, ws);
    k_scalar_early<0><<<1, 64, 0, stream>>>(ws);

    unsigned short* pl = (unsigned short*)((char*)ws + G_BASE_BYTES);
    if (ws_size >= G_BASE_BYTES + (size_t)2*6*PS*2){          // 234.5 MB
        nch[0] = 16;
        k_splitf2<0,3><<<dim3(1024,2,2), 256, 0, stream>>>(refsr, lrsr, ws, pl,
            6*PS, 0, 0, D, 1);
        k_levfin<0><<<dim3(16,2), 256, 0, stream>>>(ws, 0);
        k_g0<<<dim3(32,16,2), 512, 0, stream>>>(pl, ws, D);
    } else {                                                   // per-batch fallback
        nch[0] = 32;
        for (int b=0; b<2; b++){
            k_splitf2<0,3><<<dim3(1024,2,1), 256, 0, stream>>>(refsr, lrsr, ws, pl,
                0, b, 0, D, 1);
            k_levfin<0><<<dim3(16,1), 256, 0, stream>>>(ws, b);
            k_gmfma<0,0,3><<<dim3(32,32), 256, 0, stream>>>(pl, ws, nullptr, b, D);
        }
    }
}

// --- lev1/lev2: NSP=1 BK=64 k_g8_64 (both-batch if fits; else per-batch) ---
template<int LEV>
static void run_level(const float* refsr, const float* lrsr, float* ws,
                      size_t ws_size, hipStream_t stream, int* nch){
    constexpr int D = lev_D(LEV);
    constexpr int NSP = 1;
    k_rownorm<LEV><<<D/2, 256, 0, stream>>>(refsr, ws);
    k_scalar_early<LEV><<<1, 64, 0, stream>>>(ws);

    const size_t PS = (size_t)4096 * D;
    const size_t perBatchBytes = (size_t)2*NSP*PS*2;   // both sides, one batch
    unsigned short* pl = (unsigned short*)((char*)ws + G_BASE_BYTES);
    float* G = ws + (G_BASE_BYTES >> 2);

    if (ws_size >= G_BASE_BYTES + 2*perBatchBytes){
        nch[LEV] = 16;
        k_splitf2<LEV,NSP><<<dim3(1024,2,2), 256, 0, stream>>>(refsr, lrsr, ws, pl,
            2*NSP*PS, 0, 0, D, 1);
        k_levfin<LEV><<<dim3(16,2), 256, 0, stream>>>(ws, 0);
        k_g8_64<LEV><<<dim3(16,16,2), 512, 0, stream>>>(pl, ws, 0, D, 2*NSP*PS);
        return;
    }

    bool fused = (ws_size >= G_BASE_BYTES + perBatchBytes);
    int kd = D;
    if (!fused){
        kd = 0;
        for (int div = 2; div <= 16; div <<= 1){
            if (ws_size >= CHUNK_PLANE_BYTES + (size_t)2*NSP*4096*(D/div)*2){ kd = D/div; break; }
        }
        if (!kd) kd = D/16;
        pl = (unsigned short*)((char*)ws + CHUNK_PLANE_BYTES);
    }
    const int nkc = D / kd;
    nch[LEV] = fused ? 16 : 8;

    for (int b=0; b<2; b++){
        for (int kc=0; kc<nkc; kc++){
            k_splitf2<LEV,NSP><<<dim3(1024,2,1), 256, 0, stream>>>(refsr, lrsr, ws, pl,
                0, b, kc*kd, kd, kc==0);
            if (!fused){
                if (kc==0) k_g8<LEV,1,NSP><<<dim3(16,16,1), 512, 0, stream>>>(pl, ws, G, b, kd, 0);
                else       k_g8<LEV,2,NSP><<<dim3(16,16,1), 512, 0, stream>>>(pl, ws, G, b, kd, 0);
            }
        }
        k_levfin<LEV><<<dim3(16,1), 256, 0, stream>>>(ws, b);
        if (fused) k_g8_64<LEV><<<dim3(16,16,1), 512, 0, stream>>>(pl, ws, b, kd, 0);
        else       k_score<LEV><<<dim3(64,8), 256, 0, stream>>>(G, ws, b);
    }
}

extern "C" void kernel_launch(void* const* d_in, const int* in_sizes, int n_in,
                              void* d_out, int out_size, void* d_ws, size_t ws_size,
                              hipStream_t stream){
    const float* lrsr[3]  = { (const float*)d_in[2], (const float*)d_in[1], (const float*)d_in[0] };
    const float* refsr[3] = { (const float*)d_in[5], (const float*)d_in[4], (const float*)d_in[3] };
    const float* refp[3]  = { (const float*)d_in[8], (const float*)d_in[7], (const float*)d_in[6] };
    float* ws  = (float*)d_ws;
    float* out = (float*)d_out;

    hipMemsetAsync(d_ws, 0, 4096, stream);  // zero scalar slots + scalars

    int nch[3];
    run_level0  (refsr[0], lrsr[0], ws, ws_size, stream, nch);
    run_level<1>(refsr[1], lrsr[1], ws, ws_size, stream, nch);
    run_level<2>(refsr[2], lrsr[2], ws, ws_size, stream, nch);

    k_scalar_late_all<<<1, 64, 0, stream>>>(ws);

    k_smax<<<32, 256, 0, stream>>>(ws, out, nch[0], nch[1], nch[2]);

    k_transfer_all<<<57344, 256, 0, stream>>>(refp[0], refp[1], refp[2], ws, out);
}

// Round 14
// 2520.541 us; speedup vs baseline: 1.1502x; 1.0244x over previous
//
#include <hip/hip_runtime.h>
#include <cfloat>

// ---------------------------------------------------------------------------
// SearchTransfer (TTSR): 3-level patch correlation + argmax + gather/fold.
// Levels: 0 = lv3 (C=256,H=64,k=3,s=1,p=1,D=2304)
//         1 = lv2 (C=128,H=128,k=6,s=2,p=2,D=4608)
//         2 = lv1 (C=64,H=256,k=12,s=4,p=4,D=9216)
//
// score(l,m) = ninv[m]*G[l,m] - mval*P[l] - mval*ninv[m]*csum[m] + D*mval^2
// lev0: bf16x3 split, 6 products (exact argmax chain), k_g0 256x128
//       counted-vmcnt schedule, both batches one dispatch.
// lev1/2: single bf16 (NSP=1), 1 product, 256^2 BK=64 counted-vmcnt k_g8_64.
// Merged aux: k_rownorm_all (3 levels, 1 dispatch), k_scalar_early_all,
// scales computed inline in k_smax, k_splitf2 wave-per-row, k_transfer_all.
// ---------------------------------------------------------------------------

typedef short short8 __attribute__((ext_vector_type(8)));
typedef float f32x4  __attribute__((ext_vector_type(4)));

template<int LEV> struct LT;
template<> struct LT<0> { static constexpr int C=256, H=64,  K=3,  S=1, P=1; };
template<> struct LT<1> { static constexpr int C=128, H=128, K=6,  S=2, P=2; };
template<> struct LT<2> { static constexpr int C=64,  H=256, K=12, S=4, P=4; };

__host__ __device__ constexpr int lev_D(int lev){ return lev==0?2304:(lev==1?4608:9216); }
// ws float-index offsets
// [0,192): scalar slots: lev*64 + q*16 + slot (q:0=sum_rs,1=ssq_rs,2=sum_lr,3=ssq_lr)
// 200+lev: mval  212+lev: gx2
__host__ __device__ constexpr int rho_off(int lev){ return 256 + (lev>0?2*2304:0) + (lev>1?2*4608:0); }
__host__ __device__ constexpr int p_off(int lev)   { return 32512  + lev*8192;   }
__host__ __device__ constexpr int ninv_off(int lev){ return 57088  + lev*8192;   }
__host__ __device__ constexpr int csum_off(int lev){ return 81664  + lev*8192;   }
__host__ __device__ constexpr int pmax_off(int lev){ return 106240 + lev*262144; }
__host__ __device__ constexpr int parg_off(int lev){ return 892672 + lev*262144; }
__host__ __device__ constexpr int arg_off(){ return 1679104; }
static constexpr size_t G_BASE_BYTES      = 8ull  << 20;
static constexpr size_t CHUNK_PLANE_BYTES = 72ull << 20;

__device__ inline unsigned short f2bf(float f){
    unsigned int u = __float_as_uint(f);
    return (unsigned short)((u + 0x7fffu + ((u >> 16) & 1u)) >> 16);
}
__device__ inline float bf2f(unsigned short h){ return __uint_as_float(((unsigned)h) << 16); }

#define GLOAD16(g, l) __builtin_amdgcn_global_load_lds( \
    (const __attribute__((address_space(1))) unsigned int*)(g), \
    (__attribute__((address_space(3))) unsigned int*)(l), 16, 0, 0)

__device__ __forceinline__ void barx(){
    __builtin_amdgcn_sched_barrier(0);
    __builtin_amdgcn_s_barrier();
    __builtin_amdgcn_sched_barrier(0);
}

// --- per-(b,d) row norm of refsr unfold + rs scalar slots; ALL levels ---
template<int LEV>
__device__ __forceinline__ void rownorm_body(int blk, const float* __restrict__ refsr,
                                             float* __restrict__ ws){
    constexpr int C=LT<LEV>::C, H=LT<LEV>::H, K=LT<LEV>::K, S=LT<LEV>::S, PD=LT<LEV>::P;
    constexpr int D = C*K*K, KK=K*K;
    __shared__ float sh0[4], sh1[4];
    int tid = threadIdx.x, lane = tid & 63, w = tid >> 6;
    int wid = blk*4 + w;
    int b = wid / D, d = wid % D;
    int c = d/KK, rem = d%KK, ki = rem/K, kj = rem%K;
    const float* img = refsr + (size_t)(b*C + c)*H*H;
    float sum=0.f, ssq=0.f;
    for (int idx=lane; idx<4096; idx+=64){
        int ho=idx>>6, wo=idx&63;
        int row = ho*S+ki-PD, col = wo*S+kj-PD;
        if (row>=0 && row<H && col>=0 && col<H){
            float v = img[row*H+col]; sum += v; ssq += v*v;
        }
    }
    #pragma unroll
    for (int off=32; off; off>>=1){ sum += __shfl_xor(sum,off); ssq += __shfl_xor(ssq,off); }
    if (lane==0){
        float rinv = 1.0f / fmaxf(sqrtf(ssq), 1e-12f);
        ws[rho_off(LEV) + b*D + d] = rinv;
        sh0[w] = sum*rinv;
        sh1[w] = ssq*rinv*rinv;
    }
    __syncthreads();
    if (tid==0){
        int s = blk & 15;
        atomicAdd(&ws[LEV*64 + 0*16 + s], sh0[0]+sh0[1]+sh0[2]+sh0[3]);
        atomicAdd(&ws[LEV*64 + 1*16 + s], sh1[0]+sh1[1]+sh1[2]+sh1[3]);
    }
}

__global__ void k_rownorm_all(const float* __restrict__ rs0, const float* __restrict__ rs1,
                              const float* __restrict__ rs2, float* __restrict__ ws){
    int blk = blockIdx.x;
    if (blk < 1152)      rownorm_body<0>(blk,      rs0, ws);
    else if (blk < 3456) rownorm_body<1>(blk-1152, rs1, ws);
    else                 rownorm_body<2>(blk-3456, rs2, ws);
}

__global__ void k_scalar_early_all(float* __restrict__ ws){
    if (threadIdx.x || blockIdx.x) return;
    for (int lev=0; lev<3; lev++){
        float s0=0.f, s1=0.f;
        for (int s=0;s<16;s++){ s0 += ws[lev*64+s]; s1 += ws[lev*64+16+s]; }
        float BDL = 2.0f * (float)lev_D(lev) * 4096.0f;
        float m = s0 / BDL;
        ws[200+lev] = m;
        ws[212+lev] = s1 - 2.f*m*s0 + BDL*m*m;
    }
}

// --- MERGED fused split+stats: one WAVE per row l; side=blockIdx.y (0=rs
//     w/ rinv scaling -> P; 1=lr -> csum/ssq); batch=blockIdx.z (b=b0+z). ---
template<int LEV, int NSP>
__global__ void k_splitf2(const float* __restrict__ refsr, const float* __restrict__ lrsr,
                          float* __restrict__ ws, unsigned short* __restrict__ pl,
                          size_t bstride, int b0, int kb0, int kd, int first){
    constexpr int C=LT<LEV>::C, H=LT<LEV>::H, K=LT<LEV>::K, S=LT<LEV>::S, PD=LT<LEV>::P;
    constexpr int KK=K*K;
    const size_t PS = (size_t)4096 * kd;
    const int side = blockIdx.y;
    const int bz = blockIdx.z, b = b0 + bz;
    const int tid = threadIdx.x, lane = tid & 63, w = tid >> 6;
    const int l = blockIdx.x*4 + w;
    const int ly = l>>6, lx = l&63;
    const float* img = (side==0 ? refsr : lrsr) + (size_t)b*C*H*H;
    unsigned short* base = pl + (size_t)bz*bstride + (size_t)side*NSP*PS;
    const float* rinv = ws + rho_off(LEV) + b*lev_D(LEV);
    const int kslots = kd >> 3;
    float sum = 0.f, ssq = 0.f;
    for (int si = lane; si < kslots; si += 64){
        int kl0 = si*8;
        unsigned short h[NSP][8];
        #pragma unroll
        for (int j=0;j<8;j++){
            int k = kb0 + kl0 + j; int c=k/KK, rem=k%KK, ki=rem/K, kj=rem%K;
            int row=ly*S+ki-PD, col=lx*S+kj-PD;
            float x = (row>=0 && row<H && col>=0 && col<H)
                      ? img[(size_t)(c*H+row)*H+col] : 0.f;
            if (side==0) x *= rinv[k];
            unsigned short a = f2bf(x); h[0][j]=a;
            float rec = bf2f(a);
            if (NSP>=2){
                float r = x - bf2f(a);
                unsigned short m = f2bf(r); h[1][j]=m;
                rec += bf2f(m);
                if (NSP==3){
                    float r2 = r - bf2f(m);
                    unsigned short c2 = f2bf(r2); h[2][j]=c2;
                    rec += bf2f(c2);
                }
            }
            sum += rec; ssq += rec*rec;
        }
        int slot = si & 3, sw = slot ^ ((l>>1)&3);
        size_t off = (size_t)l*kd + (size_t)(kl0 & ~31) + sw*8;
        #pragma unroll
        for (int q=0;q<NSP;q++){
            uint4 u;
            u.x=h[q][0]|((unsigned)h[q][1]<<16); u.y=h[q][2]|((unsigned)h[q][3]<<16);
            u.z=h[q][4]|((unsigned)h[q][5]<<16); u.w=h[q][6]|((unsigned)h[q][7]<<16);
            *(uint4*)(base + q*PS + off) = u;
        }
    }
    #pragma unroll
    for (int off=32; off; off>>=1){ sum += __shfl_xor(sum,off); ssq += __shfl_xor(ssq,off); }
    if (lane==0){
        int o = b*4096 + l;
        if (side==0){
            float* P = ws + p_off(LEV);
            if (first) P[o] = sum; else P[o] += sum;
        } else {
            float* CS = ws + csum_off(LEV);
            float* SQ = ws + ninv_off(LEV);
            if (first){ CS[o] = sum; SQ[o] = ssq; }
            else      { CS[o] += sum; SQ[o] += ssq; }
        }
    }
}

// --- per-(lev, b=b0+blockIdx.y): ssq -> ninv in place; lr scalar slots ---
template<int LEV>
__global__ void k_levfin(float* __restrict__ ws, int b0){
    __shared__ float r0[4], r1[4];
    int tid = threadIdx.x, lane = tid & 63, w = tid >> 6;
    int b = b0 + blockIdx.y;
    int m = blockIdx.x*256 + tid;
    float ssq = ws[ninv_off(LEV) + b*4096 + m];
    float ninv = 1.0f / fmaxf(sqrtf(ssq), 1e-12f);
    ws[ninv_off(LEV) + b*4096 + m] = ninv;
    float y0 = ws[csum_off(LEV) + b*4096 + m] * ninv;
    float y1 = ssq * ninv * ninv;
    #pragma unroll
    for (int off=32; off; off>>=1){ y0 += __shfl_xor(y0,off); y1 += __shfl_xor(y1,off); }
    if (lane==0){ r0[w]=y0; r1[w]=y1; }
    __syncthreads();
    if (tid==0){
        int s = blockIdx.x & 15;
        atomicAdd(&ws[LEV*64 + 2*16 + s], r0[0]+r0[1]+r0[2]+r0[3]);
        atomicAdd(&ws[LEV*64 + 3*16 + s], r1[0]+r1[1]+r1[2]+r1[3]);
    }
}

// ===========================================================================
// lev0 256(l)x128(m) counted-vmcnt GEMM, NSP=3 both sides (6 products),
// fused score/max/argmax. 512 thr, 144KB LDS, both batches via blockIdx.z.
// ===========================================================================
__launch_bounds__(512, 1)
__global__ void k_g0(const unsigned short* __restrict__ planes0,
                     float* __restrict__ ws, int kd){
    const size_t PS = (size_t)4096 * kd;
    const int b = blockIdx.z;
    const unsigned short* planes = planes0 + (size_t)b*6*PS;
    __shared__ unsigned short lds[2*36864];   // 144 KB
    const int tid = threadIdx.x;
    const int w = tid >> 6, lane = tid & 63;
    const int mblk = blockIdx.x, lblk = blockIdx.y;
    const int wm = w >> 2, wn = w & 3;
    const int colrow = lane & 15, rgrp = lane >> 4;
    const int swz = (rgrp ^ ((lane >> 1) & 3)) * 8;
    const int abase = wm*4096 + colrow*32 + swz;          // + p*8192 + i*512
    const int bbase = 24576 + wn*1024 + colrow*32 + swz;  // + p*4096 + j*512
    const int NT = kd >> 5;

    f32x4 acc[8][2];
    #pragma unroll
    for (int i=0;i<8;i++){ acc[i][0]=(f32x4){0,0,0,0}; acc[i][1]=(f32x4){0,0,0,0}; }

    short8 bF[3][2];

#define STAGE0(bufv, k0v, qv) do { \
    int f = w*9 + (qv); \
    int isA = f < 48; \
    int p  = isA ? (f>>4) : ((f-48)>>3); \
    int rb = isA ? ((f&15)<<4) : (((f-48)&7)<<4); \
    const unsigned short* g = planes + (size_t)(isA ? p : 3+p)*PS \
        + (size_t)((isA ? (lblk<<8) : (mblk<<7)) + rb + (lane>>2))*kd \
        + (size_t)(k0v) + (lane&3)*8; \
    unsigned short* lp = (unsigned short*)&lds[(bufv)*36864 \
        + (isA ? p*8192 : 24576 + p*4096) + rb*32]; \
    GLOAD16(g, lp); \
} while(0)

#define RDB0(bufv) do { \
    _Pragma("unroll") \
    for (int p=0;p<3;p++) \
        _Pragma("unroll") \
        for (int j=0;j<2;j++) \
            bF[p][j] = *(const short8*)&lds[(bufv)*36864 + bbase + p*4096 + j*512]; \
} while(0)

#define MMI(bufv, i) do { \
    short8 a0 = *(const short8*)&lds[(bufv)*36864 + 0*8192 + abase + (i)*512]; \
    short8 a1 = *(const short8*)&lds[(bufv)*36864 + 1*8192 + abase + (i)*512]; \
    short8 a2 = *(const short8*)&lds[(bufv)*36864 + 2*8192 + abase + (i)*512]; \
    __builtin_amdgcn_s_setprio(1); \
    _Pragma("unroll") \
    for (int j=0;j<2;j++){ \
        acc[i][j] = __builtin_amdgcn_mfma_f32_16x16x32_bf16(a0, bF[0][j], acc[i][j],0,0,0); \
        acc[i][j] = __builtin_amdgcn_mfma_f32_16x16x32_bf16(a0, bF[1][j], acc[i][j],0,0,0); \
        acc[i][j] = __builtin_amdgcn_mfma_f32_16x16x32_bf16(a1, bF[0][j], acc[i][j],0,0,0); \
        acc[i][j] = __builtin_amdgcn_mfma_f32_16x16x32_bf16(a0, bF[2][j], acc[i][j],0,0,0); \
        acc[i][j] = __builtin_amdgcn_mfma_f32_16x16x32_bf16(a1, bF[1][j], acc[i][j],0,0,0); \
        acc[i][j] = __builtin_amdgcn_mfma_f32_16x16x32_bf16(a2, bF[0][j], acc[i][j],0,0,0); \
    } \
    __builtin_amdgcn_s_setprio(0); \
} while(0)

    STAGE0(0,0,0); STAGE0(0,0,1); STAGE0(0,0,2); STAGE0(0,0,3); STAGE0(0,0,4);
    STAGE0(0,0,5); STAGE0(0,0,6); STAGE0(0,0,7); STAGE0(0,0,8);

    int cur = 0;
    for (int kt = 0; kt < NT-1; kt++){
        const int k0n = (kt+1) << 5;
        STAGE0(cur^1, k0n, 0); STAGE0(cur^1, k0n, 1); STAGE0(cur^1, k0n, 2);
        asm volatile("s_waitcnt vmcnt(3)" ::: "memory");
        barx();
        RDB0(cur);
        MMI(cur,0); MMI(cur,1);
        STAGE0(cur^1, k0n, 3); STAGE0(cur^1, k0n, 4); STAGE0(cur^1, k0n, 5);
        MMI(cur,2); MMI(cur,3); MMI(cur,4);
        STAGE0(cur^1, k0n, 6); STAGE0(cur^1, k0n, 7); STAGE0(cur^1, k0n, 8);
        MMI(cur,5); MMI(cur,6); MMI(cur,7);
        barx();
        cur ^= 1;
    }
    asm volatile("s_waitcnt vmcnt(0)" ::: "memory");
    barx();
    RDB0(cur);
    MMI(cur,0); MMI(cur,1); MMI(cur,2); MMI(cur,3);
    MMI(cur,4); MMI(cur,5); MMI(cur,6); MMI(cur,7);

#undef STAGE0
#undef RDB0
#undef MMI

    const int lbase = (lblk<<8) + wm*128;
    const int mbase = (mblk<<7) + wn*32;
    const int D = kd;
    const float mval = ws[200];
    const float Dm2 = (float)D * mval * mval;
    const float* Pv  = ws + p_off(0)    + b*4096;
    const float* NIv = ws + ninv_off(0) + b*4096;
    const float* CSv = ws + csum_off(0) + b*4096;
    barx();
    float* smax = (float*)lds;                 // [2][128]
    int*   sarg = (int*)((char*)lds + 1024);   // [2][128]
    #pragma unroll
    for (int j=0;j<2;j++){
        int m = mbase + j*16 + colrow;
        float nv = NIv[m];
        float cmv = -mval*nv*CSv[m] + Dm2;
        float v = -FLT_MAX; int vi = 0x7fffffff;
        #pragma unroll
        for (int i=0;i<8;i++){
            #pragma unroll
            for (int rg=0; rg<4; rg++){
                int l = lbase + i*16 + rgrp*4 + rg;
                float sc = nv*acc[i][j][rg] - mval*Pv[l] + cmv;
                if (sc > v){ v = sc; vi = l; }
            }
        }
        #pragma unroll
        for (int off=16; off<64; off<<=1){
            float ov = __shfl_xor(v, off);
            int   oi = __shfl_xor(vi, off);
            if (ov > v || (ov == v && oi < vi)){ v = ov; vi = oi; }
        }
        if (rgrp == 0){
            smax[wm*128 + wn*32 + j*16 + colrow] = v;
            sarg[wm*128 + wn*32 + j*16 + colrow] = vi;
        }
    }
    barx();
    if (tid < 128){
        float v0 = smax[tid];     int a0 = sarg[tid];
        float v1 = smax[128+tid]; int a1 = sarg[128+tid];
        if (v1 > v0 || (v1 == v0 && a1 < a0)){ v0 = v1; a0 = a1; }
        int o = (b*32 + lblk)*4096 + (mblk<<7) + tid;
        ws[pmax_off(0) + o] = v0;
        ((int*)ws)[parg_off(0) + o] = a0;
    }
}

// ===========================================================================
// NSP=1 256^2 BK=64 counted-vmcnt GEMM, fused score/max/argmax.
// 512 thr, 128KB LDS. b = b0 + blockIdx.z, per-batch plane stride bstride.
// ===========================================================================
template<int LEV>
__launch_bounds__(512, 1)
__global__ void k_g8_64(const unsigned short* __restrict__ planes0,
                        float* __restrict__ ws, int b0, int kd, size_t bstride){
    const size_t PS = (size_t)4096 * kd;
    const int b = b0 + blockIdx.z;
    const unsigned short* planes = planes0 + (size_t)blockIdx.z * bstride;
    __shared__ unsigned short lds[2*32768];   // 128 KB
    const int tid = threadIdx.x;
    const int w = tid >> 6, lane = tid & 63;
    const int mblk = blockIdx.x, lblk = blockIdx.y;
    const int wm = w >> 2, wn = w & 3;
    const int colrow = lane & 15, rgrp = lane >> 4;
    const int swz = (rgrp ^ ((lane >> 1) & 3)) * 8;
    const int abase = wm*8192 + colrow*32 + swz;            // + i*1024 + h*512
    const int bbase = 16384 + wn*4096 + colrow*32 + swz;    // + j*1024 + h*512
    const int NT = kd >> 6;

    f32x4 acc[8][4];
    #pragma unroll
    for (int i=0;i<8;i++)
        #pragma unroll
        for (int j=0;j<4;j++) acc[i][j] = (f32x4){0.f,0.f,0.f,0.f};

    short8 aF[4], bF[4];

#define STG64(bufv, k0v, qv) do { \
    int flat = (qv)*8 + w; \
    int side = flat >> 5; \
    int idx = flat & 31; \
    int rowblk = idx >> 1, kc = idx & 1; \
    const unsigned short* g = planes + (size_t)side*PS \
        + (size_t)(((side ? mblk : lblk) << 8) + rowblk*16 + (lane>>2))*kd \
        + (size_t)(k0v) + kc*32 + (lane&3)*8; \
    unsigned short* lp = (unsigned short*)&lds[(bufv)*32768 + side*16384 + (rowblk*2+kc)*512]; \
    GLOAD16(g, lp); \
} while(0)

#define RDB64(bufv, h) do { \
    _Pragma("unroll") \
    for (int j=0;j<4;j++) \
        bF[j] = *(const short8*)&lds[(bufv)*32768 + bbase + j*1024 + (h)*512]; \
} while(0)

#define RDA64(bufv, h, ig) do { \
    _Pragma("unroll") \
    for (int ii=0;ii<4;ii++) \
        aF[ii] = *(const short8*)&lds[(bufv)*32768 + abase + ((ig)*4+ii)*1024 + (h)*512]; \
} while(0)

#define MMQ(ig) do { \
    __builtin_amdgcn_s_setprio(1); \
    _Pragma("unroll") \
    for (int ii=0;ii<4;ii++) \
        _Pragma("unroll") \
        for (int j=0;j<4;j++) \
            acc[(ig)*4+ii][j] = __builtin_amdgcn_mfma_f32_16x16x32_bf16( \
                                    aF[ii], bF[j], acc[(ig)*4+ii][j],0,0,0); \
    __builtin_amdgcn_s_setprio(0); \
} while(0)

    STG64(0,0,0); STG64(0,0,1); STG64(0,0,2); STG64(0,0,3);
    STG64(0,0,4); STG64(0,0,5); STG64(0,0,6); STG64(0,0,7);

    int cur = 0;
    for (int kt = 0; kt < NT-1; kt++){
        const int k0n = (kt+1) << 6;
        STG64(cur^1, k0n, 0); STG64(cur^1, k0n, 1);
        asm volatile("s_waitcnt vmcnt(2)" ::: "memory");
        barx();
        RDB64(cur,0); RDA64(cur,0,0);
        MMQ(0);
        STG64(cur^1, k0n, 2); STG64(cur^1, k0n, 3);
        RDA64(cur,0,1);
        MMQ(1);
        STG64(cur^1, k0n, 4); STG64(cur^1, k0n, 5);
        RDB64(cur,1); RDA64(cur,1,0);
        MMQ(0);
        STG64(cur^1, k0n, 6); STG64(cur^1, k0n, 7);
        RDA64(cur,1,1);
        MMQ(1);
        barx();
        cur ^= 1;
    }
    asm volatile("s_waitcnt vmcnt(0)" ::: "memory");
    barx();
    RDB64(cur,0); RDA64(cur,0,0); MMQ(0);
    RDA64(cur,0,1); MMQ(1);
    RDB64(cur,1); RDA64(cur,1,0); MMQ(0);
    RDA64(cur,1,1); MMQ(1);

#undef STG64
#undef RDB64
#undef RDA64
#undef MMQ

    const int lbase = (lblk<<8) + wm*128;
    const int mbase = (mblk<<8) + wn*64;
    constexpr int D = lev_D(LEV);
    const float mval = ws[200+LEV];
    const float Dm2 = (float)D * mval * mval;
    const float* Pv  = ws + p_off(LEV)    + b*4096;
    const float* NIv = ws + ninv_off(LEV) + b*4096;
    const float* CSv = ws + csum_off(LEV) + b*4096;
    barx();
    float* smax = (float*)lds;                 // [2][256]
    int*   sarg = (int*)((char*)lds + 2048);   // [2][256]
    #pragma unroll
    for (int j=0;j<4;j++){
        int m = mbase + j*16 + colrow;
        float nv = NIv[m];
        float cmv = -mval*nv*CSv[m] + Dm2;
        float v = -FLT_MAX; int vi = 0x7fffffff;
        #pragma unroll
        for (int i=0;i<8;i++){
            #pragma unroll
            for (int rg=0; rg<4; rg++){
                int l = lbase + i*16 + rgrp*4 + rg;
                float sc = nv*acc[i][j][rg] - mval*Pv[l] + cmv;
                if (sc > v){ v = sc; vi = l; }
            }
        }
        #pragma unroll
        for (int off=16; off<64; off<<=1){
            float ov = __shfl_xor(v, off);
            int   oi = __shfl_xor(vi, off);
            if (ov > v || (ov == v && oi < vi)){ v = ov; vi = oi; }
        }
        if (rgrp == 0){
            smax[wm*256 + wn*64 + j*16 + colrow] = v;
            sarg[wm*256 + wn*64 + j*16 + colrow] = vi;
        }
    }
    barx();
    if (tid < 256){
        float v0 = smax[tid];     int a0 = sarg[tid];
        float v1 = smax[256+tid]; int a1 = sarg[256+tid];
        if (v1 > v0 || (v1 == v0 && a1 < a0)){ v0 = v1; a0 = a1; }
        int o = (b*32 + lblk)*4096 + (mblk<<8) + tid;
        ws[pmax_off(LEV) + o] = v0;
        ((int*)ws)[parg_off(LEV) + o] = a0;
    }
}

// ===========================================================================
// 256^2 BK=32 counted-vmcnt GEMM, NSP planes/side (chunked fallback only).
// MODE 1: G = acc. MODE 2: G += acc.
// ===========================================================================
template<int LEV, int MODE, int NSP>
__launch_bounds__(512, 2)
__global__ void k_g8(const unsigned short* __restrict__ planes0,
                     float* __restrict__ ws, float* __restrict__ G,
                     int b0, int kd, size_t bstride){
    const size_t PS = (size_t)4096 * kd;
    const unsigned short* planes = planes0 + (size_t)blockIdx.z * bstride;
    __shared__ unsigned short lds[2*2*NSP*256*32];
    const int tid = threadIdx.x;
    const int w = tid >> 6, lane = tid & 63;
    const int mblk = blockIdx.x, lblk = blockIdx.y;
    const int wm = w >> 2, wn = w & 3;
    const int colrow = lane & 15, rgrp = lane >> 4;
    const int swz = (rgrp ^ ((lane >> 1) & 3)) * 8;
    const int abase = wm*4096 + colrow*32 + swz;
    const int bbase = NSP*8192 + wn*2048 + colrow*32 + swz;
    const int NT = kd >> 5;
    const int BUFS = 2*NSP*8192;

    f32x4 acc[8][4];
    #pragma unroll
    for (int i=0;i<8;i++)
        #pragma unroll
        for (int j=0;j<4;j++) acc[i][j] = (f32x4){0.f,0.f,0.f,0.f};

    short8 aF[NSP][4], bF[NSP][4];

#define STAGE(bufv, k0v, qi) do { \
    _Pragma("unroll") \
    for (int e=0;e<NSP;e++){ \
        int flat = w*(4*NSP) + (qi)*NSP + e; \
        int p = flat >> 4; \
        int rb = (flat & 15) << 4; \
        int rowbase = (p < NSP ? lblk : mblk) << 8; \
        const unsigned short* g = planes + (size_t)p*PS \
            + (size_t)(rowbase + rb + (lane>>2))*kd + (size_t)(k0v) + (lane&3)*8; \
        unsigned short* lp = (unsigned short*)&lds[(bufv)*BUFS + p*8192 + rb*32]; \
        GLOAD16(g, lp); \
    } \
} while(0)

#define RDA(bufv, half) do { \
    _Pragma("unroll") \
    for (int pl=0; pl<NSP; pl++) \
        _Pragma("unroll") \
        for (int i=0;i<4;i++) \
            aF[pl][i] = *(const short8*)&lds[(bufv)*BUFS + pl*8192 + abase + ((half)*4+i)*512]; \
} while(0)

#define RDB(bufv, half) do { \
    _Pragma("unroll") \
    for (int pl=0; pl<NSP; pl++) \
        _Pragma("unroll") \
        for (int j=0;j<2;j++) \
            bF[pl][(half)*2+j] = *(const short8*)&lds[(bufv)*BUFS + pl*8192 + bbase + ((half)*2+j)*512]; \
} while(0)

#define MM(ihalf, jhalf) do { \
    __builtin_amdgcn_s_setprio(1); \
    _Pragma("unroll") \
    for (int i=0;i<4;i++) \
        _Pragma("unroll") \
        for (int j=0;j<2;j++){ \
            const int ai = (ihalf)*4+i, bj = (jhalf)*2+j; \
            acc[ai][bj] = __builtin_amdgcn_mfma_f32_16x16x32_bf16(aF[0][i], bF[0][bj], acc[ai][bj],0,0,0); \
            if (NSP>=2){ \
                acc[ai][bj] = __builtin_amdgcn_mfma_f32_16x16x32_bf16(aF[0][i], bF[1][bj], acc[ai][bj],0,0,0); \
                acc[ai][bj] = __builtin_amdgcn_mfma_f32_16x16x32_bf16(aF[1][i], bF[0][bj], acc[ai][bj],0,0,0); \
            } \
        } \
    __builtin_amdgcn_s_setprio(0); \
} while(0)

    STAGE(0, 0, 0); STAGE(0, 0, 1); STAGE(0, 0, 2); STAGE(0, 0, 3);

    int cur = 0;
    for (int kt = 0; kt < NT-1; kt++){
        const int k0n = (kt+1) << 5;
        STAGE(cur^1, k0n, 0);
        if constexpr (NSP==1) asm volatile("s_waitcnt vmcnt(1)" ::: "memory");
        else                  asm volatile("s_waitcnt vmcnt(2)" ::: "memory");
        barx();
        RDB(cur, 0); RDA(cur, 0);
        MM(0, 0);
        STAGE(cur^1, k0n, 1);
        RDB(cur, 1);
        MM(0, 1);
        STAGE(cur^1, k0n, 2);
        RDA(cur, 1);
        MM(1, 1);
        STAGE(cur^1, k0n, 3);
        MM(1, 0);
        barx();
        cur ^= 1;
    }
    asm volatile("s_waitcnt vmcnt(0)" ::: "memory");
    barx();
    RDB(cur, 0); RDA(cur, 0); MM(0, 0);
    RDB(cur, 1); MM(0, 1);
    RDA(cur, 1); MM(1, 1);
    MM(1, 0);

#undef STAGE
#undef RDA
#undef RDB
#undef MM

    const int lbase = (lblk<<8) + wm*128;
    const int mbase = (mblk<<8) + wn*64;

    #pragma unroll
    for (int i=0;i<8;i++){
        #pragma unroll
        for (int rg=0; rg<4; rg++){
            float* gp = G + (size_t)(lbase + i*16 + rgrp*4 + rg)*4096 + mbase + colrow;
            #pragma unroll
            for (int j=0;j<4;j++){
                float v = acc[i][j][rg];
                if (MODE == 2) v += gp[j*16];
                gp[j*16] = v;
            }
        }
    }
}

// --- OLD 128^2 MFMA GEMM (fallback for lev0 if ws too small) ---
template<int LEV, int MODE, int NSP>
__launch_bounds__(256, 2)
__global__ void k_gmfma(const unsigned short* __restrict__ planes,
                        float* __restrict__ ws, float* __restrict__ G,
                        int b, int kd){
    const size_t PS = (size_t)4096 * kd;
    __shared__ unsigned short lds[2*NSP*128*32];
    const int tid = threadIdx.x;
    const int w = tid >> 6, lane = tid & 63;
    const int mblk = blockIdx.x, lblk = blockIdx.y;
    const int lw = w >> 1, mw = w & 1;

    f32x4 acc[4][4];
    #pragma unroll
    for (int i=0;i<4;i++)
        #pragma unroll
        for (int j=0;j<4;j++) acc[i][j] = (f32x4){0.f,0.f,0.f,0.f};

    const int srow = lane >> 2, ssl = lane & 3;
    const int colrow = lane & 15, kk = lane >> 4;
    const int swz = (kk ^ ((lane >> 1) & 3)) * 8;
    const int aRow0 = lw*64 + colrow;
    const int bRow0 = mw*64 + colrow;

    for (int k0 = 0; k0 < kd; k0 += 32){
        #pragma unroll
        for (int p = 0; p < 2*NSP; p++){
            const int rb = (p < NSP ? lblk : mblk)*128 + w*32 + srow;
            const unsigned short* gp0 = planes + (size_t)p*PS
                                        + (size_t)rb*kd + (size_t)k0 + ssl*8;
            unsigned short* lp0 = &lds[p*4096 + w*1024];
            GLOAD16(gp0, lp0);
            GLOAD16(gp0 + (size_t)16*kd, lp0 + 512);
        }
        __syncthreads();

        short8 aF[NSP][4];
        #pragma unroll
        for (int pa=0; pa<NSP; pa++)
            #pragma unroll
            for (int i=0;i<4;i++)
                aF[pa][i] = *(const short8*)&lds[pa*4096 + (aRow0 + i*16)*32 + swz];
        #pragma unroll
        for (int pb=0; pb<NSP; pb++){
            short8 bF[4];
            #pragma unroll
            for (int j=0;j<4;j++)
                bF[j] = *(const short8*)&lds[(NSP+pb)*4096 + (bRow0 + j*16)*32 + swz];
            const int npa = NSP - pb;
            for (int pa=0; pa<npa; pa++)
                #pragma unroll
                for (int i=0;i<4;i++)
                    #pragma unroll
                    for (int j=0;j<4;j++)
                        acc[i][j] = __builtin_amdgcn_mfma_f32_16x16x32_bf16(
                                        aF[pa][i], bF[j], acc[i][j], 0, 0, 0);
        }
        __syncthreads();
    }

    const int lbase = lblk*128 + lw*64;
    const int mbase = mblk*128 + mw*64;
    const int rgrp = lane >> 4;

    if (MODE != 0){
        #pragma unroll
        for (int i=0;i<4;i++){
            #pragma unroll
            for (int rg=0; rg<4; rg++){
                float* gp = G + (size_t)(lbase + i*16 + rgrp*4 + rg)*4096
                              + mbase + colrow;
                #pragma unroll
                for (int j=0;j<4;j++){
                    float v = acc[i][j][rg];
                    if (MODE == 2) v += gp[j*16];
                    gp[j*16] = v;
                }
            }
        }
        return;
    }

    constexpr int D = lev_D(LEV);
    const float mval = ws[200+LEV];
    const float Dm2 = (float)D * mval * mval;
    const float* Pv  = ws + p_off(LEV)    + b*4096;
    const float* NIv = ws + ninv_off(LEV) + b*4096;
    const float* CSv = ws + csum_off(LEV) + b*4096;
    float* smax = (float*)lds;
    int*   sarg = (int*)&lds[512];
    #pragma unroll
    for (int j=0;j<4;j++){
        int m = mbase + j*16 + colrow;
        float nv = NIv[m];
        float cmv = -mval*nv*CSv[m] + Dm2;
        float v = -FLT_MAX; int vi = 0x7fffffff;
        #pragma unroll
        for (int i=0;i<4;i++){
            #pragma unroll
            for (int rg=0; rg<4; rg++){
                int l = lbase + i*16 + rgrp*4 + rg;
                float sc = nv*acc[i][j][rg] - mval*Pv[l] + cmv;
                if (sc > v){ v = sc; vi = l; }
            }
        }
        #pragma unroll
        for (int off=16; off<64; off<<=1){
            float ov = __shfl_xor(v, off);
            int   oi = __shfl_xor(vi, off);
            if (ov > v || (ov == v && oi < vi)){ v = ov; vi = oi; }
        }
        if (rgrp == 0){
            smax[w*64 + j*16 + colrow] = v;
            sarg[w*64 + j*16 + colrow] = vi;
        }
    }
    __syncthreads();
    if (tid < 128){
        int mg = tid >> 6, idx = tid & 63;
        float v0 = smax[mg*64 + idx];     int a0 = sarg[mg*64 + idx];
        float v1 = smax[(mg+2)*64 + idx]; int a1 = sarg[(mg+2)*64 + idx];
        if (v1 > v0 || (v1 == v0 && a1 < a0)){ v0 = v1; a0 = a1; }
        int m = mblk*128 + mg*64 + idx;
        int o = (b*32 + lblk)*4096 + m;
        ws[pmax_off(LEV) + o] = v0;
        ((int*)ws)[parg_off(LEV) + o] = a0;
    }
}

// --- score + max/argmax from accumulated G; grid (64 mblk, 8 lsplit) ---
template<int LEV>
__global__ void k_score(const float* __restrict__ G, float* __restrict__ ws, int b){
    constexpr int D = lev_D(LEV);
    __shared__ float smax[4][64];
    __shared__ int   sarg[4][64];
    int tid = threadIdx.x, mloc = tid & 63, r = tid >> 6;
    int m = blockIdx.x*64 + mloc;
    int l0 = blockIdx.y*512;
    float mval = ws[200+LEV];
    float nv = ws[ninv_off(LEV) + b*4096 + m];
    float cmv = -mval*nv*ws[csum_off(LEV) + b*4096 + m] + (float)D*mval*mval;
    const float* Pv = ws + p_off(LEV) + b*4096;
    float best = -FLT_MAX; int bi = 0x7fffffff;
    for (int lt=0; lt<128; lt++){
        int l = l0 + lt*4 + r;
        float sc = nv*G[(size_t)l*4096 + m] - mval*Pv[l] + cmv;
        if (sc > best){ best = sc; bi = l; }
    }
    smax[r][mloc] = best; sarg[r][mloc] = bi;
    __syncthreads();
    if (tid < 64){
        float v = smax[0][tid]; int vi = sarg[0][tid];
        #pragma unroll
        for (int rr=1; rr<4; rr++){
            float ov = smax[rr][tid]; int oi = sarg[rr][tid];
            if (ov > v || (ov == v && oi < vi)){ v = ov; vi = oi; }
        }
        int o = (b*32 + blockIdx.y)*4096 + blockIdx.x*64 + tid;
        ws[pmax_off(LEV) + o] = v;
        ((int*)ws)[parg_off(LEV) + o] = vi;
    }
}

// --- reduce l-chunks -> outputs; scales computed inline (incl. ym3 bug) ---
__global__ void k_smax(float* __restrict__ ws, float* __restrict__ out,
                       int nch0, int nch1, int nch2){
    int gid = blockIdx.x*256 + threadIdx.x;
    if (gid >= 8192) return;
    float scale[3];
    {
        float gy2_0 = 0.f;
        for (int lev=0; lev<3; lev++){
            float s2=0.f, s3=0.f;
            for (int s=0;s<16;s++){ s2 += ws[lev*64+32+s]; s3 += ws[lev*64+48+s]; }
            float BDL = 2.0f * (float)lev_D(lev) * 4096.0f;
            float m = ws[200+lev];
            float gy2 = s3 - 2.f*m*s2 + BDL*m*m;
            if (lev==0) gy2_0 = gy2;
            float gx2 = ws[212+lev];
            float gyu = (lev==1) ? gy2_0 : gy2;
            scale[lev] = 1.0f/(sqrtf(gx2)*sqrtf(gyu));
        }
    }
    int b = gid >> 12, m = gid & 4095;
    int nchs[3] = {nch0, nch1, nch2};
    for (int lev=0; lev<3; lev++){
        float mv = -FLT_MAX; int ma = 0x7fffffff;
        for (int ch=0; ch<nchs[lev]; ch++){
            int o = ((b*32+ch)<<12) + m;
            float v = ws[pmax_off(lev) + o];
            int   a = ((const int*)ws)[parg_off(lev) + o];
            if (v > mv || (v == mv && a < ma)){ mv=v; ma=a; }
        }
        out[lev*8192 + gid] = mv * scale[lev];
        if (lev==0){
            out[3*8192 + gid] = (float)ma;
            ((int*)ws)[arg_off() + gid] = ma;
        }
    }
}

// --- T = fold(gather(unfold(ref), arg)) / 9 ; all 3 levels in one grid ---
template<int LEV>
__device__ __forceinline__ void transfer_body(int blk, const float* __restrict__ ref,
                                              const float* __restrict__ wsf,
                                              float* __restrict__ outT){
    constexpr int C=LT<LEV>::C, H=LT<LEV>::H, K=LT<LEV>::K, S=LT<LEV>::S, PD=LT<LEV>::P;
    const int* arg = (const int*)wsf + arg_off();
    size_t gid = (size_t)blk*256 + threadIdx.x;
    int x = (int)(gid % H);
    int y = (int)((gid / H) % H);
    int c = (int)((gid / ((size_t)H*H)) % C);
    int b = (int)(gid / ((size_t)C*H*H));
    const float* rimg = ref + (size_t)(b*C+c)*H*H;
    int byo = (y+PD)/S, ryo = (y+PD)%S;
    int bxo = (x+PD)/S, rxo = (x+PD)%S;
    float acc = 0.f;
    #pragma unroll
    for (int jy=0; jy<3; jy++){
        int ho = byo - jy;
        if (ho < 0 || ho >= 64) continue;
        int ki = ryo + jy*S;
        #pragma unroll
        for (int jx=0; jx<3; jx++){
            int wo = bxo - jx;
            if (wo < 0 || wo >= 64) continue;
            int kj = rxo + jx*S;
            int l = arg[b*4096 + ho*64 + wo];
            int ly = l>>6, lx = l&63;
            int srow = ly*S + ki - PD, scol = lx*S + kj - PD;
            if (srow>=0 && srow<H && scol>=0 && scol<H)
                acc += rimg[srow*H + scol];
        }
    }
    outT[gid] = acc * (1.0f/9.0f);
}

__global__ void k_transfer_all(const float* __restrict__ r0, const float* __restrict__ r1,
                               const float* __restrict__ r2, const float* __restrict__ wsf,
                               float* __restrict__ out){
    int blk = blockIdx.x;
    if (blk < 8192)       transfer_body<0>(blk,        r0, wsf, out + 32768);
    else if (blk < 24576) transfer_body<1>(blk-8192,   r1, wsf, out + 2129920);
    else                  transfer_body<2>(blk-24576,  r2, wsf, out + 6324224);
}

// --- lev0: bf16x3, k_g0 both-batch path (fallback: per-batch k_gmfma) ---
static void run_level0(const float* refsr, const float* lrsr, float* ws,
                       size_t ws_size, hipStream_t stream, int* nch){
    constexpr int D = 2304;
    const size_t PS = (size_t)4096 * D;
    unsigned short* pl = (unsigned short*)((char*)ws + G_BASE_BYTES);
    if (ws_size >= G_BASE_BYTES + (size_t)2*6*PS*2){          // 234.5 MB
        nch[0] = 16;
        k_splitf2<0,3><<<dim3(1024,2,2), 256, 0, stream>>>(refsr, lrsr, ws, pl,
            6*PS, 0, 0, D, 1);
        k_levfin<0><<<dim3(16,2), 256, 0, stream>>>(ws, 0);
        k_g0<<<dim3(32,16,2), 512, 0, stream>>>(pl, ws, D);
    } else {                                                   // per-batch fallback
        nch[0] = 32;
        for (int b=0; b<2; b++){
            k_splitf2<0,3><<<dim3(1024,2,1), 256, 0, stream>>>(refsr, lrsr, ws, pl,
                0, b, 0, D, 1);
            k_levfin<0><<<dim3(16,1), 256, 0, stream>>>(ws, b);
            k_gmfma<0,0,3><<<dim3(32,32), 256, 0, stream>>>(pl, ws, nullptr, b, D);
        }
    }
}

// --- lev1/lev2: NSP=1 BK=64 k_g8_64 (both-batch if fits; else per-batch) ---
template<int LEV>
static void run_level(const float* refsr, const float* lrsr, float* ws,
                      size_t ws_size, hipStream_t stream, int* nch){
    constexpr int D = lev_D(LEV);
    constexpr int NSP = 1;
    const size_t PS = (size_t)4096 * D;
    const size_t perBatchBytes = (size_t)2*NSP*PS*2;   // both sides, one batch
    unsigned short* pl = (unsigned short*)((char*)ws + G_BASE_BYTES);
    float* G = ws + (G_BASE_BYTES >> 2);

    if (ws_size >= G_BASE_BYTES + 2*perBatchBytes){
        nch[LEV] = 16;
        k_splitf2<LEV,NSP><<<dim3(1024,2,2), 256, 0, stream>>>(refsr, lrsr, ws, pl,
            2*NSP*PS, 0, 0, D, 1);
        k_levfin<LEV><<<dim3(16,2), 256, 0, stream>>>(ws, 0);
        k_g8_64<LEV><<<dim3(16,16,2), 512, 0, stream>>>(pl, ws, 0, D, 2*NSP*PS);
        return;
    }

    bool fused = (ws_size >= G_BASE_BYTES + perBatchBytes);
    int kd = D;
    if (!fused){
        kd = 0;
        for (int div = 2; div <= 16; div <<= 1){
            if (ws_size >= CHUNK_PLANE_BYTES + (size_t)2*NSP*4096*(D/div)*2){ kd = D/div; break; }
        }
        if (!kd) kd = D/16;
        pl = (unsigned short*)((char*)ws + CHUNK_PLANE_BYTES);
    }
    const int nkc = D / kd;
    nch[LEV] = fused ? 16 : 8;

    for (int b=0; b<2; b++){
        for (int kc=0; kc<nkc; kc++){
            k_splitf2<LEV,NSP><<<dim3(1024,2,1), 256, 0, stream>>>(refsr, lrsr, ws, pl,
                0, b, kc*kd, kd, kc==0);
            if (!fused){
                if (kc==0) k_g8<LEV,1,NSP><<<dim3(16,16,1), 512, 0, stream>>>(pl, ws, G, b, kd, 0);
                else       k_g8<LEV,2,NSP><<<dim3(16,16,1), 512, 0, stream>>>(pl, ws, G, b, kd, 0);
            }
        }
        k_levfin<LEV><<<dim3(16,1), 256, 0, stream>>>(ws, b);
        if (fused) k_g8_64<LEV><<<dim3(16,16,1), 512, 0, stream>>>(pl, ws, b, kd, 0);
        else       k_score<LEV><<<dim3(64,8), 256, 0, stream>>>(G, ws, b);
    }
}

extern "C" void kernel_launch(void* const* d_in, const int* in_sizes, int n_in,
                              void* d_out, int out_size, void* d_ws, size_t ws_size,
                              hipStream_t stream){
    const float* lrsr[3]  = { (const float*)d_in[2], (const float*)d_in[1], (const float*)d_in[0] };
    const float* refsr[3] = { (const float*)d_in[5], (const float*)d_in[4], (const float*)d_in[3] };
    const float* refp[3]  = { (const float*)d_in[8], (const float*)d_in[7], (const float*)d_in[6] };
    float* ws  = (float*)d_ws;
    float* out = (float*)d_out;

    hipMemsetAsync(d_ws, 0, 4096, stream);  // zero scalar slots + scalars

    k_rownorm_all<<<8064, 256, 0, stream>>>(refsr[0], refsr[1], refsr[2], ws);
    k_scalar_early_all<<<1, 64, 0, stream>>>(ws);

    int nch[3];
    run_level0  (refsr[0], lrsr[0], ws, ws_size, stream, nch);
    run_level<1>(refsr[1], lrsr[1], ws, ws_size, stream, nch);
    run_level<2>(refsr[2], lrsr[2], ws, ws_size, stream, nch);

    k_smax<<<32, 256, 0, stream>>>(ws, out, nch[0], nch[1], nch[2]);

    k_transfer_all<<<57344, 256, 0, stream>>>(refp[0], refp[1], refp[2], ws, out);
}

// Round 15
// 2215.917 us; speedup vs baseline: 1.3083x; 1.1375x over previous
//
#include <hip/hip_runtime.h>
#include <cfloat>

// ---------------------------------------------------------------------------
// SearchTransfer (TTSR): 3-level patch correlation + argmax + gather/fold.
// Levels: 0 = lv3 (C=256,H=64,k=3,s=1,p=1,D=2304)
//         1 = lv2 (C=128,H=128,k=6,s=2,p=2,D=4608)
//         2 = lv1 (C=64,H=256,k=12,s=4,p=4,D=9216)
//
// score(l,m) = ninv[m]*G[l,m] - mval*P[l] - mval*ninv[m]*csum[m] + D*mval^2
// lev0: bf16x2 split, 3 products (error ~4e-6|G| — same class as the
//       argmax-exact fp32-chain R1), k_g0 256x128 counted-vmcnt schedule.
// lev1/2: single bf16 (NSP=1), 1 product, 256^2 BK=64 counted-vmcnt k_g8_64.
// Merged aux: k_rownorm_all, k_scalar_early_all, scales inline in k_smax,
// k_splitf2 wave-per-row, k_transfer_all.
// ---------------------------------------------------------------------------

typedef short short8 __attribute__((ext_vector_type(8)));
typedef float f32x4  __attribute__((ext_vector_type(4)));

template<int LEV> struct LT;
template<> struct LT<0> { static constexpr int C=256, H=64,  K=3,  S=1, P=1; };
template<> struct LT<1> { static constexpr int C=128, H=128, K=6,  S=2, P=2; };
template<> struct LT<2> { static constexpr int C=64,  H=256, K=12, S=4, P=4; };

__host__ __device__ constexpr int lev_D(int lev){ return lev==0?2304:(lev==1?4608:9216); }
// ws float-index offsets
// [0,192): scalar slots: lev*64 + q*16 + slot (q:0=sum_rs,1=ssq_rs,2=sum_lr,3=ssq_lr)
// 200+lev: mval  212+lev: gx2
__host__ __device__ constexpr int rho_off(int lev){ return 256 + (lev>0?2*2304:0) + (lev>1?2*4608:0); }
__host__ __device__ constexpr int p_off(int lev)   { return 32512  + lev*8192;   }
__host__ __device__ constexpr int ninv_off(int lev){ return 57088  + lev*8192;   }
__host__ __device__ constexpr int csum_off(int lev){ return 81664  + lev*8192;   }
__host__ __device__ constexpr int pmax_off(int lev){ return 106240 + lev*262144; }
__host__ __device__ constexpr int parg_off(int lev){ return 892672 + lev*262144; }
__host__ __device__ constexpr int arg_off(){ return 1679104; }
static constexpr size_t G_BASE_BYTES      = 8ull  << 20;
static constexpr size_t CHUNK_PLANE_BYTES = 72ull << 20;

__device__ inline unsigned short f2bf(float f){
    unsigned int u = __float_as_uint(f);
    return (unsigned short)((u + 0x7fffu + ((u >> 16) & 1u)) >> 16);
}
__device__ inline float bf2f(unsigned short h){ return __uint_as_float(((unsigned)h) << 16); }

#define GLOAD16(g, l) __builtin_amdgcn_global_load_lds( \
    (const __attribute__((address_space(1))) unsigned int*)(g), \
    (__attribute__((address_space(3))) unsigned int*)(l), 16, 0, 0)

__device__ __forceinline__ void barx(){
    __builtin_amdgcn_sched_barrier(0);
    __builtin_amdgcn_s_barrier();
    __builtin_amdgcn_sched_barrier(0);
}

// --- per-(b,d) row norm of refsr unfold + rs scalar slots; ALL levels ---
template<int LEV>
__device__ __forceinline__ void rownorm_body(int blk, const float* __restrict__ refsr,
                                             float* __restrict__ ws){
    constexpr int C=LT<LEV>::C, H=LT<LEV>::H, K=LT<LEV>::K, S=LT<LEV>::S, PD=LT<LEV>::P;
    constexpr int D = C*K*K, KK=K*K;
    __shared__ float sh0[4], sh1[4];
    int tid = threadIdx.x, lane = tid & 63, w = tid >> 6;
    int wid = blk*4 + w;
    int b = wid / D, d = wid % D;
    int c = d/KK, rem = d%KK, ki = rem/K, kj = rem%K;
    const float* img = refsr + (size_t)(b*C + c)*H*H;
    float sum=0.f, ssq=0.f;
    for (int idx=lane; idx<4096; idx+=64){
        int ho=idx>>6, wo=idx&63;
        int row = ho*S+ki-PD, col = wo*S+kj-PD;
        if (row>=0 && row<H && col>=0 && col<H){
            float v = img[row*H+col]; sum += v; ssq += v*v;
        }
    }
    #pragma unroll
    for (int off=32; off; off>>=1){ sum += __shfl_xor(sum,off); ssq += __shfl_xor(ssq,off); }
    if (lane==0){
        float rinv = 1.0f / fmaxf(sqrtf(ssq), 1e-12f);
        ws[rho_off(LEV) + b*D + d] = rinv;
        sh0[w] = sum*rinv;
        sh1[w] = ssq*rinv*rinv;
    }
    __syncthreads();
    if (tid==0){
        int s = blk & 15;
        atomicAdd(&ws[LEV*64 + 0*16 + s], sh0[0]+sh0[1]+sh0[2]+sh0[3]);
        atomicAdd(&ws[LEV*64 + 1*16 + s], sh1[0]+sh1[1]+sh1[2]+sh1[3]);
    }
}

__global__ void k_rownorm_all(const float* __restrict__ rs0, const float* __restrict__ rs1,
                              const float* __restrict__ rs2, float* __restrict__ ws){
    int blk = blockIdx.x;
    if (blk < 1152)      rownorm_body<0>(blk,      rs0, ws);
    else if (blk < 3456) rownorm_body<1>(blk-1152, rs1, ws);
    else                 rownorm_body<2>(blk-3456, rs2, ws);
}

__global__ void k_scalar_early_all(float* __restrict__ ws){
    if (threadIdx.x || blockIdx.x) return;
    for (int lev=0; lev<3; lev++){
        float s0=0.f, s1=0.f;
        for (int s=0;s<16;s++){ s0 += ws[lev*64+s]; s1 += ws[lev*64+16+s]; }
        float BDL = 2.0f * (float)lev_D(lev) * 4096.0f;
        float m = s0 / BDL;
        ws[200+lev] = m;
        ws[212+lev] = s1 - 2.f*m*s0 + BDL*m*m;
    }
}

// --- MERGED fused split+stats: one WAVE per row l; side=blockIdx.y (0=rs
//     w/ rinv scaling -> P; 1=lr -> csum/ssq); batch=blockIdx.z (b=b0+z). ---
template<int LEV, int NSP>
__global__ void k_splitf2(const float* __restrict__ refsr, const float* __restrict__ lrsr,
                          float* __restrict__ ws, unsigned short* __restrict__ pl,
                          size_t bstride, int b0, int kb0, int kd, int first){
    constexpr int C=LT<LEV>::C, H=LT<LEV>::H, K=LT<LEV>::K, S=LT<LEV>::S, PD=LT<LEV>::P;
    constexpr int KK=K*K;
    const size_t PS = (size_t)4096 * kd;
    const int side = blockIdx.y;
    const int bz = blockIdx.z, b = b0 + bz;
    const int tid = threadIdx.x, lane = tid & 63, w = tid >> 6;
    const int l = blockIdx.x*4 + w;
    const int ly = l>>6, lx = l&63;
    const float* img = (side==0 ? refsr : lrsr) + (size_t)b*C*H*H;
    unsigned short* base = pl + (size_t)bz*bstride + (size_t)side*NSP*PS;
    const float* rinv = ws + rho_off(LEV) + b*lev_D(LEV);
    const int kslots = kd >> 3;
    float sum = 0.f, ssq = 0.f;
    for (int si = lane; si < kslots; si += 64){
        int kl0 = si*8;
        unsigned short h[NSP][8];
        #pragma unroll
        for (int j=0;j<8;j++){
            int k = kb0 + kl0 + j; int c=k/KK, rem=k%KK, ki=rem/K, kj=rem%K;
            int row=ly*S+ki-PD, col=lx*S+kj-PD;
            float x = (row>=0 && row<H && col>=0 && col<H)
                      ? img[(size_t)(c*H+row)*H+col] : 0.f;
            if (side==0) x *= rinv[k];
            unsigned short a = f2bf(x); h[0][j]=a;
            float rec = bf2f(a);
            if (NSP>=2){
                float r = x - bf2f(a);
                unsigned short m = f2bf(r); h[1][j]=m;
                rec += bf2f(m);
                if (NSP==3){
                    float r2 = r - bf2f(m);
                    unsigned short c2 = f2bf(r2); h[2][j]=c2;
                    rec += bf2f(c2);
                }
            }
            sum += rec; ssq += rec*rec;
        }
        int slot = si & 3, sw = slot ^ ((l>>1)&3);
        size_t off = (size_t)l*kd + (size_t)(kl0 & ~31) + sw*8;
        #pragma unroll
        for (int q=0;q<NSP;q++){
            uint4 u;
            u.x=h[q][0]|((unsigned)h[q][1]<<16); u.y=h[q][2]|((unsigned)h[q][3]<<16);
            u.z=h[q][4]|((unsigned)h[q][5]<<16); u.w=h[q][6]|((unsigned)h[q][7]<<16);
            *(uint4*)(base + q*PS + off) = u;
        }
    }
    #pragma unroll
    for (int off=32; off; off>>=1){ sum += __shfl_xor(sum,off); ssq += __shfl_xor(ssq,off); }
    if (lane==0){
        int o = b*4096 + l;
        if (side==0){
            float* P = ws + p_off(LEV);
            if (first) P[o] = sum; else P[o] += sum;
        } else {
            float* CS = ws + csum_off(LEV);
            float* SQ = ws + ninv_off(LEV);
            if (first){ CS[o] = sum; SQ[o] = ssq; }
            else      { CS[o] += sum; SQ[o] += ssq; }
        }
    }
}

// --- per-(lev, b=b0+blockIdx.y): ssq -> ninv in place; lr scalar slots ---
template<int LEV>
__global__ void k_levfin(float* __restrict__ ws, int b0){
    __shared__ float r0[4], r1[4];
    int tid = threadIdx.x, lane = tid & 63, w = tid >> 6;
    int b = b0 + blockIdx.y;
    int m = blockIdx.x*256 + tid;
    float ssq = ws[ninv_off(LEV) + b*4096 + m];
    float ninv = 1.0f / fmaxf(sqrtf(ssq), 1e-12f);
    ws[ninv_off(LEV) + b*4096 + m] = ninv;
    float y0 = ws[csum_off(LEV) + b*4096 + m] * ninv;
    float y1 = ssq * ninv * ninv;
    #pragma unroll
    for (int off=32; off; off>>=1){ y0 += __shfl_xor(y0,off); y1 += __shfl_xor(y1,off); }
    if (lane==0){ r0[w]=y0; r1[w]=y1; }
    __syncthreads();
    if (tid==0){
        int s = blockIdx.x & 15;
        atomicAdd(&ws[LEV*64 + 2*16 + s], r0[0]+r0[1]+r0[2]+r0[3]);
        atomicAdd(&ws[LEV*64 + 3*16 + s], r1[0]+r1[1]+r1[2]+r1[3]);
    }
}

// ===========================================================================
// lev0 256(l)x128(m) counted-vmcnt GEMM, NSP=2 both sides (3 products:
// a0b0 + a0b1 + a1b0), fused score/max/argmax. 512 thr, 96KB LDS,
// both batches via blockIdx.z. Planes: rs 0..1, lr 2..3.
// ===========================================================================
__launch_bounds__(512, 1)
__global__ void k_g0(const unsigned short* __restrict__ planes0,
                     float* __restrict__ ws, int kd){
    const size_t PS = (size_t)4096 * kd;
    const int b = blockIdx.z;
    const unsigned short* planes = planes0 + (size_t)b*4*PS;
    __shared__ unsigned short lds[2*24576];   // 96 KB
    const int tid = threadIdx.x;
    const int w = tid >> 6, lane = tid & 63;
    const int mblk = blockIdx.x, lblk = blockIdx.y;
    const int wm = w >> 2, wn = w & 3;
    const int colrow = lane & 15, rgrp = lane >> 4;
    const int swz = (rgrp ^ ((lane >> 1) & 3)) * 8;
    const int abase = wm*4096 + colrow*32 + swz;          // + p*8192 + i*512
    const int bbase = 16384 + wn*1024 + colrow*32 + swz;  // + p*4096 + j*512
    const int NT = kd >> 5;

    f32x4 acc[8][2];
    #pragma unroll
    for (int i=0;i<8;i++){ acc[i][0]=(f32x4){0,0,0,0}; acc[i][1]=(f32x4){0,0,0,0}; }

    short8 bF[2][2];

#define STAGE0(bufv, k0v, qv) do { \
    int f = w*6 + (qv); \
    int isA = f < 32; \
    int p  = isA ? (f>>4) : ((f-32)>>3); \
    int rb = isA ? ((f&15)<<4) : (((f-32)&7)<<4); \
    const unsigned short* g = planes + (size_t)(isA ? p : 2+p)*PS \
        + (size_t)((isA ? (lblk<<8) : (mblk<<7)) + rb + (lane>>2))*kd \
        + (size_t)(k0v) + (lane&3)*8; \
    unsigned short* lp = (unsigned short*)&lds[(bufv)*24576 \
        + (isA ? p*8192 : 16384 + p*4096) + rb*32]; \
    GLOAD16(g, lp); \
} while(0)

#define RDB0(bufv) do { \
    _Pragma("unroll") \
    for (int p=0;p<2;p++) \
        _Pragma("unroll") \
        for (int j=0;j<2;j++) \
            bF[p][j] = *(const short8*)&lds[(bufv)*24576 + bbase + p*4096 + j*512]; \
} while(0)

#define MMI(bufv, i) do { \
    short8 a0 = *(const short8*)&lds[(bufv)*24576 + 0*8192 + abase + (i)*512]; \
    short8 a1 = *(const short8*)&lds[(bufv)*24576 + 1*8192 + abase + (i)*512]; \
    __builtin_amdgcn_s_setprio(1); \
    _Pragma("unroll") \
    for (int j=0;j<2;j++){ \
        acc[i][j] = __builtin_amdgcn_mfma_f32_16x16x32_bf16(a0, bF[0][j], acc[i][j],0,0,0); \
        acc[i][j] = __builtin_amdgcn_mfma_f32_16x16x32_bf16(a0, bF[1][j], acc[i][j],0,0,0); \
        acc[i][j] = __builtin_amdgcn_mfma_f32_16x16x32_bf16(a1, bF[0][j], acc[i][j],0,0,0); \
    } \
    __builtin_amdgcn_s_setprio(0); \
} while(0)

    STAGE0(0,0,0); STAGE0(0,0,1); STAGE0(0,0,2);
    STAGE0(0,0,3); STAGE0(0,0,4); STAGE0(0,0,5);

    int cur = 0;
    for (int kt = 0; kt < NT-1; kt++){
        const int k0n = (kt+1) << 5;
        STAGE0(cur^1, k0n, 0); STAGE0(cur^1, k0n, 1);
        asm volatile("s_waitcnt vmcnt(2)" ::: "memory");
        barx();                       // current tile resident for all waves
        RDB0(cur);
        MMI(cur,0); MMI(cur,1);
        STAGE0(cur^1, k0n, 2); STAGE0(cur^1, k0n, 3);
        MMI(cur,2); MMI(cur,3); MMI(cur,4);
        STAGE0(cur^1, k0n, 4); STAGE0(cur^1, k0n, 5);
        MMI(cur,5); MMI(cur,6); MMI(cur,7);
        barx();                       // reads of buf[cur] done before reuse
        cur ^= 1;
    }
    asm volatile("s_waitcnt vmcnt(0)" ::: "memory");
    barx();
    RDB0(cur);
    MMI(cur,0); MMI(cur,1); MMI(cur,2); MMI(cur,3);
    MMI(cur,4); MMI(cur,5); MMI(cur,6); MMI(cur,7);

#undef STAGE0
#undef RDB0
#undef MMI

    const int lbase = (lblk<<8) + wm*128;
    const int mbase = (mblk<<7) + wn*32;
    const int D = kd;
    const float mval = ws[200];
    const float Dm2 = (float)D * mval * mval;
    const float* Pv  = ws + p_off(0)    + b*4096;
    const float* NIv = ws + ninv_off(0) + b*4096;
    const float* CSv = ws + csum_off(0) + b*4096;
    barx();
    float* smax = (float*)lds;                 // [2][128]
    int*   sarg = (int*)((char*)lds + 1024);   // [2][128]
    #pragma unroll
    for (int j=0;j<2;j++){
        int m = mbase + j*16 + colrow;
        float nv = NIv[m];
        float cmv = -mval*nv*CSv[m] + Dm2;
        float v = -FLT_MAX; int vi = 0x7fffffff;
        #pragma unroll
        for (int i=0;i<8;i++){
            #pragma unroll
            for (int rg=0; rg<4; rg++){
                int l = lbase + i*16 + rgrp*4 + rg;
                float sc = nv*acc[i][j][rg] - mval*Pv[l] + cmv;
                if (sc > v){ v = sc; vi = l; }
            }
        }
        #pragma unroll
        for (int off=16; off<64; off<<=1){
            float ov = __shfl_xor(v, off);
            int   oi = __shfl_xor(vi, off);
            if (ov > v || (ov == v && oi < vi)){ v = ov; vi = oi; }
        }
        if (rgrp == 0){
            smax[wm*128 + wn*32 + j*16 + colrow] = v;
            sarg[wm*128 + wn*32 + j*16 + colrow] = vi;
        }
    }
    barx();
    if (tid < 128){
        float v0 = smax[tid];     int a0 = sarg[tid];
        float v1 = smax[128+tid]; int a1 = sarg[128+tid];
        if (v1 > v0 || (v1 == v0 && a1 < a0)){ v0 = v1; a0 = a1; }
        int o = (b*32 + lblk)*4096 + (mblk<<7) + tid;
        ws[pmax_off(0) + o] = v0;
        ((int*)ws)[parg_off(0) + o] = a0;
    }
}

// ===========================================================================
// NSP=1 256^2 BK=64 counted-vmcnt GEMM, fused score/max/argmax.
// 512 thr, 128KB LDS. b = b0 + blockIdx.z, per-batch plane stride bstride.
// ===========================================================================
template<int LEV>
__launch_bounds__(512, 1)
__global__ void k_g8_64(const unsigned short* __restrict__ planes0,
                        float* __restrict__ ws, int b0, int kd, size_t bstride){
    const size_t PS = (size_t)4096 * kd;
    const int b = b0 + blockIdx.z;
    const unsigned short* planes = planes0 + (size_t)blockIdx.z * bstride;
    __shared__ unsigned short lds[2*32768];   // 128 KB
    const int tid = threadIdx.x;
    const int w = tid >> 6, lane = tid & 63;
    const int mblk = blockIdx.x, lblk = blockIdx.y;
    const int wm = w >> 2, wn = w & 3;
    const int colrow = lane & 15, rgrp = lane >> 4;
    const int swz = (rgrp ^ ((lane >> 1) & 3)) * 8;
    const int abase = wm*8192 + colrow*32 + swz;            // + i*1024 + h*512
    const int bbase = 16384 + wn*4096 + colrow*32 + swz;    // + j*1024 + h*512
    const int NT = kd >> 6;

    f32x4 acc[8][4];
    #pragma unroll
    for (int i=0;i<8;i++)
        #pragma unroll
        for (int j=0;j<4;j++) acc[i][j] = (f32x4){0.f,0.f,0.f,0.f};

    short8 aF[4], bF[4];

#define STG64(bufv, k0v, qv) do { \
    int flat = (qv)*8 + w; \
    int side = flat >> 5; \
    int idx = flat & 31; \
    int rowblk = idx >> 1, kc = idx & 1; \
    const unsigned short* g = planes + (size_t)side*PS \
        + (size_t)(((side ? mblk : lblk) << 8) + rowblk*16 + (lane>>2))*kd \
        + (size_t)(k0v) + kc*32 + (lane&3)*8; \
    unsigned short* lp = (unsigned short*)&lds[(bufv)*32768 + side*16384 + (rowblk*2+kc)*512]; \
    GLOAD16(g, lp); \
} while(0)

#define RDB64(bufv, h) do { \
    _Pragma("unroll") \
    for (int j=0;j<4;j++) \
        bF[j] = *(const short8*)&lds[(bufv)*32768 + bbase + j*1024 + (h)*512]; \
} while(0)

#define RDA64(bufv, h, ig) do { \
    _Pragma("unroll") \
    for (int ii=0;ii<4;ii++) \
        aF[ii] = *(const short8*)&lds[(bufv)*32768 + abase + ((ig)*4+ii)*1024 + (h)*512]; \
} while(0)

#define MMQ(ig) do { \
    __builtin_amdgcn_s_setprio(1); \
    _Pragma("unroll") \
    for (int ii=0;ii<4;ii++) \
        _Pragma("unroll") \
        for (int j=0;j<4;j++) \
            acc[(ig)*4+ii][j] = __builtin_amdgcn_mfma_f32_16x16x32_bf16( \
                                    aF[ii], bF[j], acc[(ig)*4+ii][j],0,0,0); \
    __builtin_amdgcn_s_setprio(0); \
} while(0)

    STG64(0,0,0); STG64(0,0,1); STG64(0,0,2); STG64(0,0,3);
    STG64(0,0,4); STG64(0,0,5); STG64(0,0,6); STG64(0,0,7);

    int cur = 0;
    for (int kt = 0; kt < NT-1; kt++){
        const int k0n = (kt+1) << 6;
        STG64(cur^1, k0n, 0); STG64(cur^1, k0n, 1);
        asm volatile("s_waitcnt vmcnt(2)" ::: "memory");
        barx();
        RDB64(cur,0); RDA64(cur,0,0);
        MMQ(0);
        STG64(cur^1, k0n, 2); STG64(cur^1, k0n, 3);
        RDA64(cur,0,1);
        MMQ(1);
        STG64(cur^1, k0n, 4); STG64(cur^1, k0n, 5);
        RDB64(cur,1); RDA64(cur,1,0);
        MMQ(0);
        STG64(cur^1, k0n, 6); STG64(cur^1, k0n, 7);
        RDA64(cur,1,1);
        MMQ(1);
        barx();
        cur ^= 1;
    }
    asm volatile("s_waitcnt vmcnt(0)" ::: "memory");
    barx();
    RDB64(cur,0); RDA64(cur,0,0); MMQ(0);
    RDA64(cur,0,1); MMQ(1);
    RDB64(cur,1); RDA64(cur,1,0); MMQ(0);
    RDA64(cur,1,1); MMQ(1);

#undef STG64
#undef RDB64
#undef RDA64
#undef MMQ

    const int lbase = (lblk<<8) + wm*128;
    const int mbase = (mblk<<8) + wn*64;
    constexpr int D = lev_D(LEV);
    const float mval = ws[200+LEV];
    const float Dm2 = (float)D * mval * mval;
    const float* Pv  = ws + p_off(LEV)    + b*4096;
    const float* NIv = ws + ninv_off(LEV) + b*4096;
    const float* CSv = ws + csum_off(LEV) + b*4096;
    barx();
    float* smax = (float*)lds;                 // [2][256]
    int*   sarg = (int*)((char*)lds + 2048);   // [2][256]
    #pragma unroll
    for (int j=0;j<4;j++){
        int m = mbase + j*16 + colrow;
        float nv = NIv[m];
        float cmv = -mval*nv*CSv[m] + Dm2;
        float v = -FLT_MAX; int vi = 0x7fffffff;
        #pragma unroll
        for (int i=0;i<8;i++){
            #pragma unroll
            for (int rg=0; rg<4; rg++){
                int l = lbase + i*16 + rgrp*4 + rg;
                float sc = nv*acc[i][j][rg] - mval*Pv[l] + cmv;
                if (sc > v){ v = sc; vi = l; }
            }
        }
        #pragma unroll
        for (int off=16; off<64; off<<=1){
            float ov = __shfl_xor(v, off);
            int   oi = __shfl_xor(vi, off);
            if (ov > v || (ov == v && oi < vi)){ v = ov; vi = oi; }
        }
        if (rgrp == 0){
            smax[wm*256 + wn*64 + j*16 + colrow] = v;
            sarg[wm*256 + wn*64 + j*16 + colrow] = vi;
        }
    }
    barx();
    if (tid < 256){
        float v0 = smax[tid];     int a0 = sarg[tid];
        float v1 = smax[256+tid]; int a1 = sarg[256+tid];
        if (v1 > v0 || (v1 == v0 && a1 < a0)){ v0 = v1; a0 = a1; }
        int o = (b*32 + lblk)*4096 + (mblk<<8) + tid;
        ws[pmax_off(LEV) + o] = v0;
        ((int*)ws)[parg_off(LEV) + o] = a0;
    }
}

// ===========================================================================
// 256^2 BK=32 counted-vmcnt GEMM, NSP planes/side (chunked fallback only).
// MODE 1: G = acc. MODE 2: G += acc.
// ===========================================================================
template<int LEV, int MODE, int NSP>
__launch_bounds__(512, 2)
__global__ void k_g8(const unsigned short* __restrict__ planes0,
                     float* __restrict__ ws, float* __restrict__ G,
                     int b0, int kd, size_t bstride){
    const size_t PS = (size_t)4096 * kd;
    const unsigned short* planes = planes0 + (size_t)blockIdx.z * bstride;
    __shared__ unsigned short lds[2*2*NSP*256*32];
    const int tid = threadIdx.x;
    const int w = tid >> 6, lane = tid & 63;
    const int mblk = blockIdx.x, lblk = blockIdx.y;
    const int wm = w >> 2, wn = w & 3;
    const int colrow = lane & 15, rgrp = lane >> 4;
    const int swz = (rgrp ^ ((lane >> 1) & 3)) * 8;
    const int abase = wm*4096 + colrow*32 + swz;
    const int bbase = NSP*8192 + wn*2048 + colrow*32 + swz;
    const int NT = kd >> 5;
    const int BUFS = 2*NSP*8192;

    f32x4 acc[8][4];
    #pragma unroll
    for (int i=0;i<8;i++)
        #pragma unroll
        for (int j=0;j<4;j++) acc[i][j] = (f32x4){0.f,0.f,0.f,0.f};

    short8 aF[NSP][4], bF[NSP][4];

#define STAGE(bufv, k0v, qi) do { \
    _Pragma("unroll") \
    for (int e=0;e<NSP;e++){ \
        int flat = w*(4*NSP) + (qi)*NSP + e; \
        int p = flat >> 4; \
        int rb = (flat & 15) << 4; \
        int rowbase = (p < NSP ? lblk : mblk) << 8; \
        const unsigned short* g = planes + (size_t)p*PS \
            + (size_t)(rowbase + rb + (lane>>2))*kd + (size_t)(k0v) + (lane&3)*8; \
        unsigned short* lp = (unsigned short*)&lds[(bufv)*BUFS + p*8192 + rb*32]; \
        GLOAD16(g, lp); \
    } \
} while(0)

#define RDA(bufv, half) do { \
    _Pragma("unroll") \
    for (int pl=0; pl<NSP; pl++) \
        _Pragma("unroll") \
        for (int i=0;i<4;i++) \
            aF[pl][i] = *(const short8*)&lds[(bufv)*BUFS + pl*8192 + abase + ((half)*4+i)*512]; \
} while(0)

#define RDB(bufv, half) do { \
    _Pragma("unroll") \
    for (int pl=0; pl<NSP; pl++) \
        _Pragma("unroll") \
        for (int j=0;j<2;j++) \
            bF[pl][(half)*2+j] = *(const short8*)&lds[(bufv)*BUFS + pl*8192 + bbase + ((half)*2+j)*512]; \
} while(0)

#define MM(ihalf, jhalf) do { \
    __builtin_amdgcn_s_setprio(1); \
    _Pragma("unroll") \
    for (int i=0;i<4;i++) \
        _Pragma("unroll") \
        for (int j=0;j<2;j++){ \
            const int ai = (ihalf)*4+i, bj = (jhalf)*2+j; \
            acc[ai][bj] = __builtin_amdgcn_mfma_f32_16x16x32_bf16(aF[0][i], bF[0][bj], acc[ai][bj],0,0,0); \
            if (NSP>=2){ \
                acc[ai][bj] = __builtin_amdgcn_mfma_f32_16x16x32_bf16(aF[0][i], bF[1][bj], acc[ai][bj],0,0,0); \
                acc[ai][bj] = __builtin_amdgcn_mfma_f32_16x16x32_bf16(aF[1][i], bF[0][bj], acc[ai][bj],0,0,0); \
            } \
        } \
    __builtin_amdgcn_s_setprio(0); \
} while(0)

    STAGE(0, 0, 0); STAGE(0, 0, 1); STAGE(0, 0, 2); STAGE(0, 0, 3);

    int cur = 0;
    for (int kt = 0; kt < NT-1; kt++){
        const int k0n = (kt+1) << 5;
        STAGE(cur^1, k0n, 0);
        if constexpr (NSP==1) asm volatile("s_waitcnt vmcnt(1)" ::: "memory");
        else                  asm volatile("s_waitcnt vmcnt(2)" ::: "memory");
        barx();
        RDB(cur, 0); RDA(cur, 0);
        MM(0, 0);
        STAGE(cur^1, k0n, 1);
        RDB(cur, 1);
        MM(0, 1);
        STAGE(cur^1, k0n, 2);
        RDA(cur, 1);
        MM(1, 1);
        STAGE(cur^1, k0n, 3);
        MM(1, 0);
        barx();
        cur ^= 1;
    }
    asm volatile("s_waitcnt vmcnt(0)" ::: "memory");
    barx();
    RDB(cur, 0); RDA(cur, 0); MM(0, 0);
    RDB(cur, 1); MM(0, 1);
    RDA(cur, 1); MM(1, 1);
    MM(1, 0);

#undef STAGE
#undef RDA
#undef RDB
#undef MM

    const int lbase = (lblk<<8) + wm*128;
    const int mbase = (mblk<<8) + wn*64;

    #pragma unroll
    for (int i=0;i<8;i++){
        #pragma unroll
        for (int rg=0; rg<4; rg++){
            float* gp = G + (size_t)(lbase + i*16 + rgrp*4 + rg)*4096 + mbase + colrow;
            #pragma unroll
            for (int j=0;j<4;j++){
                float v = acc[i][j][rg];
                if (MODE == 2) v += gp[j*16];
                gp[j*16] = v;
            }
        }
    }
}

// --- OLD 128^2 MFMA GEMM (fallback for lev0 if ws too small) ---
template<int LEV, int MODE, int NSP>
__launch_bounds__(256, 2)
__global__ void k_gmfma(const unsigned short* __restrict__ planes,
                        float* __restrict__ ws, float* __restrict__ G,
                        int b, int kd){
    const size_t PS = (size_t)4096 * kd;
    __shared__ unsigned short lds[2*NSP*128*32];
    const int tid = threadIdx.x;
    const int w = tid >> 6, lane = tid & 63;
    const int mblk = blockIdx.x, lblk = blockIdx.y;
    const int lw = w >> 1, mw = w & 1;

    f32x4 acc[4][4];
    #pragma unroll
    for (int i=0;i<4;i++)
        #pragma unroll
        for (int j=0;j<4;j++) acc[i][j] = (f32x4){0.f,0.f,0.f,0.f};

    const int srow = lane >> 2, ssl = lane & 3;
    const int colrow = lane & 15, kk = lane >> 4;
    const int swz = (kk ^ ((lane >> 1) & 3)) * 8;
    const int aRow0 = lw*64 + colrow;
    const int bRow0 = mw*64 + colrow;

    for (int k0 = 0; k0 < kd; k0 += 32){
        #pragma unroll
        for (int p = 0; p < 2*NSP; p++){
            const int rb = (p < NSP ? lblk : mblk)*128 + w*32 + srow;
            const unsigned short* gp0 = planes + (size_t)p*PS
                                        + (size_t)rb*kd + (size_t)k0 + ssl*8;
            unsigned short* lp0 = &lds[p*4096 + w*1024];
            GLOAD16(gp0, lp0);
            GLOAD16(gp0 + (size_t)16*kd, lp0 + 512);
        }
        __syncthreads();

        short8 aF[NSP][4];
        #pragma unroll
        for (int pa=0; pa<NSP; pa++)
            #pragma unroll
            for (int i=0;i<4;i++)
                aF[pa][i] = *(const short8*)&lds[pa*4096 + (aRow0 + i*16)*32 + swz];
        #pragma unroll
        for (int pb=0; pb<NSP; pb++){
            short8 bF[4];
            #pragma unroll
            for (int j=0;j<4;j++)
                bF[j] = *(const short8*)&lds[(NSP+pb)*4096 + (bRow0 + j*16)*32 + swz];
            const int npa = NSP - pb;
            for (int pa=0; pa<npa; pa++)
                #pragma unroll
                for (int i=0;i<4;i++)
                    #pragma unroll
                    for (int j=0;j<4;j++)
                        acc[i][j] = __builtin_amdgcn_mfma_f32_16x16x32_bf16(
                                        aF[pa][i], bF[j], acc[i][j], 0, 0, 0);
        }
        __syncthreads();
    }

    const int lbase = lblk*128 + lw*64;
    const int mbase = mblk*128 + mw*64;
    const int rgrp = lane >> 4;

    if (MODE != 0){
        #pragma unroll
        for (int i=0;i<4;i++){
            #pragma unroll
            for (int rg=0; rg<4; rg++){
                float* gp = G + (size_t)(lbase + i*16 + rgrp*4 + rg)*4096
                              + mbase + colrow;
                #pragma unroll
                for (int j=0;j<4;j++){
                    float v = acc[i][j][rg];
                    if (MODE == 2) v += gp[j*16];
                    gp[j*16] = v;
                }
            }
        }
        return;
    }

    constexpr int D = lev_D(LEV);
    const float mval = ws[200+LEV];
    const float Dm2 = (float)D * mval * mval;
    const float* Pv  = ws + p_off(LEV)    + b*4096;
    const float* NIv = ws + ninv_off(LEV) + b*4096;
    const float* CSv = ws + csum_off(LEV) + b*4096;
    float* smax = (float*)lds;
    int*   sarg = (int*)&lds[512];
    #pragma unroll
    for (int j=0;j<4;j++){
        int m = mbase + j*16 + colrow;
        float nv = NIv[m];
        float cmv = -mval*nv*CSv[m] + Dm2;
        float v = -FLT_MAX; int vi = 0x7fffffff;
        #pragma unroll
        for (int i=0;i<4;i++){
            #pragma unroll
            for (int rg=0; rg<4; rg++){
                int l = lbase + i*16 + rgrp*4 + rg;
                float sc = nv*acc[i][j][rg] - mval*Pv[l] + cmv;
                if (sc > v){ v = sc; vi = l; }
            }
        }
        #pragma unroll
        for (int off=16; off<64; off<<=1){
            float ov = __shfl_xor(v, off);
            int   oi = __shfl_xor(vi, off);
            if (ov > v || (ov == v && oi < vi)){ v = ov; vi = oi; }
        }
        if (rgrp == 0){
            smax[w*64 + j*16 + colrow] = v;
            sarg[w*64 + j*16 + colrow] = vi;
        }
    }
    __syncthreads();
    if (tid < 128){
        int mg = tid >> 6, idx = tid & 63;
        float v0 = smax[mg*64 + idx];     int a0 = sarg[mg*64 + idx];
        float v1 = smax[(mg+2)*64 + idx]; int a1 = sarg[(mg+2)*64 + idx];
        if (v1 > v0 || (v1 == v0 && a1 < a0)){ v0 = v1; a0 = a1; }
        int m = mblk*128 + mg*64 + idx;
        int o = (b*32 + lblk)*4096 + m;
        ws[pmax_off(LEV) + o] = v0;
        ((int*)ws)[parg_off(LEV) + o] = a0;
    }
}

// --- score + max/argmax from accumulated G; grid (64 mblk, 8 lsplit) ---
template<int LEV>
__global__ void k_score(const float* __restrict__ G, float* __restrict__ ws, int b){
    constexpr int D = lev_D(LEV);
    __shared__ float smax[4][64];
    __shared__ int   sarg[4][64];
    int tid = threadIdx.x, mloc = tid & 63, r = tid >> 6;
    int m = blockIdx.x*64 + mloc;
    int l0 = blockIdx.y*512;
    float mval = ws[200+LEV];
    float nv = ws[ninv_off(LEV) + b*4096 + m];
    float cmv = -mval*nv*ws[csum_off(LEV) + b*4096 + m] + (float)D*mval*mval;
    const float* Pv = ws + p_off(LEV) + b*4096;
    float best = -FLT_MAX; int bi = 0x7fffffff;
    for (int lt=0; lt<128; lt++){
        int l = l0 + lt*4 + r;
        float sc = nv*G[(size_t)l*4096 + m] - mval*Pv[l] + cmv;
        if (sc > best){ best = sc; bi = l; }
    }
    smax[r][mloc] = best; sarg[r][mloc] = bi;
    __syncthreads();
    if (tid < 64){
        float v = smax[0][tid]; int vi = sarg[0][tid];
        #pragma unroll
        for (int rr=1; rr<4; rr++){
            float ov = smax[rr][tid]; int oi = sarg[rr][tid];
            if (ov > v || (ov == v && oi < vi)){ v = ov; vi = oi; }
        }
        int o = (b*32 + blockIdx.y)*4096 + blockIdx.x*64 + tid;
        ws[pmax_off(LEV) + o] = v;
        ((int*)ws)[parg_off(LEV) + o] = vi;
    }
}

// --- reduce l-chunks -> outputs; scales computed inline (incl. ym3 bug) ---
__global__ void k_smax(float* __restrict__ ws, float* __restrict__ out,
                       int nch0, int nch1, int nch2){
    int gid = blockIdx.x*256 + threadIdx.x;
    if (gid >= 8192) return;
    float scale[3];
    {
        float gy2_0 = 0.f;
        for (int lev=0; lev<3; lev++){
            float s2=0.f, s3=0.f;
            for (int s=0;s<16;s++){ s2 += ws[lev*64+32+s]; s3 += ws[lev*64+48+s]; }
            float BDL = 2.0f * (float)lev_D(lev) * 4096.0f;
            float m = ws[200+lev];
            float gy2 = s3 - 2.f*m*s2 + BDL*m*m;
            if (lev==0) gy2_0 = gy2;
            float gx2 = ws[212+lev];
            float gyu = (lev==1) ? gy2_0 : gy2;
            scale[lev] = 1.0f/(sqrtf(gx2)*sqrtf(gyu));
        }
    }
    int b = gid >> 12, m = gid & 4095;
    int nchs[3] = {nch0, nch1, nch2};
    for (int lev=0; lev<3; lev++){
        float mv = -FLT_MAX; int ma = 0x7fffffff;
        for (int ch=0; ch<nchs[lev]; ch++){
            int o = ((b*32+ch)<<12) + m;
            float v = ws[pmax_off(lev) + o];
            int   a = ((const int*)ws)[parg_off(lev) + o];
            if (v > mv || (v == mv && a < ma)){ mv=v; ma=a; }
        }
        out[lev*8192 + gid] = mv * scale[lev];
        if (lev==0){
            out[3*8192 + gid] = (float)ma;
            ((int*)ws)[arg_off() + gid] = ma;
        }
    }
}

// --- T = fold(gather(unfold(ref), arg)) / 9 ; all 3 levels in one grid ---
template<int LEV>
__device__ __forceinline__ void transfer_body(int blk, const float* __restrict__ ref,
                                              const float* __restrict__ wsf,
                                              float* __restrict__ outT){
    constexpr int C=LT<LEV>::C, H=LT<LEV>::H, K=LT<LEV>::K, S=LT<LEV>::S, PD=LT<LEV>::P;
    const int* arg = (const int*)wsf + arg_off();
    size_t gid = (size_t)blk*256 + threadIdx.x;
    int x = (int)(gid % H);
    int y = (int)((gid / H) % H);
    int c = (int)((gid / ((size_t)H*H)) % C);
    int b = (int)(gid / ((size_t)C*H*H));
    const float* rimg = ref + (size_t)(b*C+c)*H*H;
    int byo = (y+PD)/S, ryo = (y+PD)%S;
    int bxo = (x+PD)/S, rxo = (x+PD)%S;
    float acc = 0.f;
    #pragma unroll
    for (int jy=0; jy<3; jy++){
        int ho = byo - jy;
        if (ho < 0 || ho >= 64) continue;
        int ki = ryo + jy*S;
        #pragma unroll
        for (int jx=0; jx<3; jx++){
            int wo = bxo - jx;
            if (wo < 0 || wo >= 64) continue;
            int kj = rxo + jx*S;
            int l = arg[b*4096 + ho*64 + wo];
            int ly = l>>6, lx = l&63;
            int srow = ly*S + ki - PD, scol = lx*S + kj - PD;
            if (srow>=0 && srow<H && scol>=0 && scol<H)
                acc += rimg[srow*H + scol];
        }
    }
    outT[gid] = acc * (1.0f/9.0f);
}

__global__ void k_transfer_all(const float* __restrict__ r0, const float* __restrict__ r1,
                               const float* __restrict__ r2, const float* __restrict__ wsf,
                               float* __restrict__ out){
    int blk = blockIdx.x;
    if (blk < 8192)       transfer_body<0>(blk,        r0, wsf, out + 32768);
    else if (blk < 24576) transfer_body<1>(blk-8192,   r1, wsf, out + 2129920);
    else                  transfer_body<2>(blk-24576,  r2, wsf, out + 6324224);
}

// --- lev0: bf16x2, k_g0 both-batch path (fallback: per-batch NSP=3 k_gmfma) ---
static void run_level0(const float* refsr, const float* lrsr, float* ws,
                       size_t ws_size, hipStream_t stream, int* nch){
    constexpr int D = 2304;
    const size_t PS = (size_t)4096 * D;
    unsigned short* pl = (unsigned short*)((char*)ws + G_BASE_BYTES);
    if (ws_size >= G_BASE_BYTES + (size_t)2*4*PS*2){          // 159 MB
        nch[0] = 16;
        k_splitf2<0,2><<<dim3(1024,2,2), 256, 0, stream>>>(refsr, lrsr, ws, pl,
            4*PS, 0, 0, D, 1);
        k_levfin<0><<<dim3(16,2), 256, 0, stream>>>(ws, 0);
        k_g0<<<dim3(32,16,2), 512, 0, stream>>>(pl, ws, D);
    } else {                                                   // per-batch fallback
        nch[0] = 32;
        for (int b=0; b<2; b++){
            k_splitf2<0,3><<<dim3(1024,2,1), 256, 0, stream>>>(refsr, lrsr, ws, pl,
                0, b, 0, D, 1);
            k_levfin<0><<<dim3(16,1), 256, 0, stream>>>(ws, b);
            k_gmfma<0,0,3><<<dim3(32,32), 256, 0, stream>>>(pl, ws, nullptr, b, D);
        }
    }
}

// --- lev1/lev2: NSP=1 BK=64 k_g8_64 (both-batch if fits; else per-batch) ---
template<int LEV>
static void run_level(const float* refsr, const float* lrsr, float* ws,
                      size_t ws_size, hipStream_t stream, int* nch){
    constexpr int D = lev_D(LEV);
    constexpr int NSP = 1;
    const size_t PS = (size_t)4096 * D;
    const size_t perBatchBytes = (size_t)2*NSP*PS*2;   // both sides, one batch
    unsigned short* pl = (unsigned short*)((char*)ws + G_BASE_BYTES);
    float* G = ws + (G_BASE_BYTES >> 2);

    if (ws_size >= G_BASE_BYTES + 2*perBatchBytes){
        nch[LEV] = 16;
        k_splitf2<LEV,NSP><<<dim3(1024,2,2), 256, 0, stream>>>(refsr, lrsr, ws, pl,
            2*NSP*PS, 0, 0, D, 1);
        k_levfin<LEV><<<dim3(16,2), 256, 0, stream>>>(ws, 0);
        k_g8_64<LEV><<<dim3(16,16,2), 512, 0, stream>>>(pl, ws, 0, D, 2*NSP*PS);
        return;
    }

    bool fused = (ws_size >= G_BASE_BYTES + perBatchBytes);
    int kd = D;
    if (!fused){
        kd = 0;
        for (int div = 2; div <= 16; div <<= 1){
            if (ws_size >= CHUNK_PLANE_BYTES + (size_t)2*NSP*4096*(D/div)*2){ kd = D/div; break; }
        }
        if (!kd) kd = D/16;
        pl = (unsigned short*)((char*)ws + CHUNK_PLANE_BYTES);
    }
    const int nkc = D / kd;
    nch[LEV] = fused ? 16 : 8;

    for (int b=0; b<2; b++){
        for (int kc=0; kc<nkc; kc++){
            k_splitf2<LEV,NSP><<<dim3(1024,2,1), 256, 0, stream>>>(refsr, lrsr, ws, pl,
                0, b, kc*kd, kd, kc==0);
            if (!fused){
                if (kc==0) k_g8<LEV,1,NSP><<<dim3(16,16,1), 512, 0, stream>>>(pl, ws, G, b, kd, 0);
                else       k_g8<LEV,2,NSP><<<dim3(16,16,1), 512, 0, stream>>>(pl, ws, G, b, kd, 0);
            }
        }
        k_levfin<LEV><<<dim3(16,1), 256, 0, stream>>>(ws, b);
        if (fused) k_g8_64<LEV><<<dim3(16,16,1), 512, 0, stream>>>(pl, ws, b, kd, 0);
        else       k_score<LEV><<<dim3(64,8), 256, 0, stream>>>(G, ws, b);
    }
}

extern "C" void kernel_launch(void* const* d_in, const int* in_sizes, int n_in,
                              void* d_out, int out_size, void* d_ws, size_t ws_size,
                              hipStream_t stream){
    const float* lrsr[3]  = { (const float*)d_in[2], (const float*)d_in[1], (const float*)d_in[0] };
    const float* refsr[3] = { (const float*)d_in[5], (const float*)d_in[4], (const float*)d_in[3] };
    const float* refp[3]  = { (const float*)d_in[8], (const float*)d_in[7], (const float*)d_in[6] };
    float* ws  = (float*)d_ws;
    float* out = (float*)d_out;

    hipMemsetAsync(d_ws, 0, 4096, stream);  // zero scalar slots + scalars

    k_rownorm_all<<<8064, 256, 0, stream>>>(refsr[0], refsr[1], refsr[2], ws);
    k_scalar_early_all<<<1, 64, 0, stream>>>(ws);

    int nch[3];
    run_level0  (refsr[0], lrsr[0], ws, ws_size, stream, nch);
    run_level<1>(refsr[1], lrsr[1], ws, ws_size, stream, nch);
    run_level<2>(refsr[2], lrsr[2], ws, ws_size, stream, nch);

    k_smax<<<32, 256, 0, stream>>>(ws, out, nch[0], nch[1], nch[2]);

    k_transfer_all<<<57344, 256, 0, stream>>>(refp[0], refp[1], refp[2], ws, out);
}